// Round 1
// baseline (760.820 us; speedup 1.0000x reference)
//
#include <hip/hip_runtime.h>
#include <math.h>

#define N_NODES 100000
#define N_EDGES 1600000
#define E2 (N_EDGES + N_NODES)
#define NEG_SLOPE 0.2f

// ---------------- CSR construction ----------------

__global__ __launch_bounds__(256) void k_init(int* deg, int* cursor) {
  int i = blockIdx.x * 256 + threadIdx.x;
  if (i < N_NODES) { deg[i] = 1; cursor[i] = 0; }  // deg starts at 1: self-loop
}

__global__ __launch_bounds__(256) void k_hist(const int* __restrict__ ei, int* __restrict__ deg) {
  int e = blockIdx.x * 256 + threadIdx.x;
  if (e < N_EDGES) atomicAdd(&deg[ei[N_EDGES + e]], 1);
}

__global__ __launch_bounds__(1024) void k_scan1(const int* __restrict__ deg,
                                                int* __restrict__ rowptr,
                                                int* __restrict__ blocksum) {
  __shared__ int sm[1024];
  int idx = blockIdx.x * 1024 + threadIdx.x;
  int v = (idx < N_NODES) ? deg[idx] : 0;
  sm[threadIdx.x] = v;
  __syncthreads();
  for (int off = 1; off < 1024; off <<= 1) {
    int t = (threadIdx.x >= off) ? sm[threadIdx.x - off] : 0;
    __syncthreads();
    sm[threadIdx.x] += t;
    __syncthreads();
  }
  if (idx < N_NODES) rowptr[idx + 1] = sm[threadIdx.x];
  if (threadIdx.x == 1023) blocksum[blockIdx.x] = sm[1023];
}

__global__ __launch_bounds__(128) void k_scan2(const int* __restrict__ blocksum,
                                               int* __restrict__ blockoff, int nb) {
  __shared__ int sm[128];
  int v = (threadIdx.x < nb) ? blocksum[threadIdx.x] : 0;
  sm[threadIdx.x] = v;
  __syncthreads();
  for (int off = 1; off < 128; off <<= 1) {
    int t = (threadIdx.x >= off) ? sm[threadIdx.x - off] : 0;
    __syncthreads();
    sm[threadIdx.x] += t;
    __syncthreads();
  }
  if (threadIdx.x < nb) blockoff[threadIdx.x] = (threadIdx.x == 0) ? 0 : sm[threadIdx.x - 1];
}

__global__ __launch_bounds__(1024) void k_scan3(int* __restrict__ rowptr,
                                                const int* __restrict__ blockoff) {
  int idx = blockIdx.x * 1024 + threadIdx.x;
  if (idx < N_NODES) rowptr[idx + 1] += blockoff[blockIdx.x];
  if (idx == 0) rowptr[0] = 0;
}

__global__ __launch_bounds__(256) void k_fill(const int* __restrict__ ei,
                                              const int* __restrict__ rowptr,
                                              int* __restrict__ cursor,
                                              int* __restrict__ csr) {
  int e = blockIdx.x * 256 + threadIdx.x;
  if (e >= E2) return;
  int s, d;
  if (e < N_EDGES) { s = ei[e]; d = ei[N_EDGES + e]; }
  else { s = e - N_EDGES; d = s; }
  int pos = atomicAdd(&cursor[d], 1);
  csr[rowptr[d] + pos] = s;
}

// ---------------- GEMM 1: h1 = x @ W1  [N,128]x[128,128] ----------------

__global__ __launch_bounds__(256) void k_gemm1(const float* __restrict__ x,
                                               const float* __restrict__ W1,
                                               float* __restrict__ h1) {
  __shared__ float wsm[64 * 128];   // K-half of W: [64][128]
  __shared__ float xsm[32 * 68];    // x tile: [32 rows][64 k] pad->68
  const int tid = threadIdx.x;
  const int tx = tid & 15;          // col group: cols tx*8 .. tx*8+7
  const int ty = tid >> 4;          // 0..15 -> rows 2ty, 2ty+1
  const int gbase = blockIdx.x * 32;  // 3125*32 == 100000 exactly
  float acc[2][8] = {};
  const float4* W4 = (const float4*)W1;  // [128][32]
  const float4* X4 = (const float4*)x;   // [N][32]
  float4* ws4 = (float4*)wsm;
  float4* xs4 = (float4*)xsm;            // row stride 17 float4
  for (int p = 0; p < 2; ++p) {
#pragma unroll
    for (int i = 0; i < 8; ++i) {
      int l4 = tid + i * 256;            // 0..2047
      ws4[l4] = W4[p * 2048 + l4];
    }
#pragma unroll
    for (int i = 0; i < 2; ++i) {
      int l4 = tid + i * 256;            // 0..511
      int r = l4 >> 4, c4 = l4 & 15;
      xs4[r * 17 + c4] = X4[(size_t)(gbase + r) * 32 + p * 16 + c4];
    }
    __syncthreads();
#pragma unroll 4
    for (int k = 0; k < 64; ++k) {
      float a0 = xsm[(2 * ty) * 68 + k];
      float a1 = xsm[(2 * ty + 1) * 68 + k];
      float4 w0 = *(const float4*)&wsm[k * 128 + tx * 8];
      float4 w1 = *(const float4*)&wsm[k * 128 + tx * 8 + 4];
      acc[0][0] += a0 * w0.x; acc[0][1] += a0 * w0.y; acc[0][2] += a0 * w0.z; acc[0][3] += a0 * w0.w;
      acc[0][4] += a0 * w1.x; acc[0][5] += a0 * w1.y; acc[0][6] += a0 * w1.z; acc[0][7] += a0 * w1.w;
      acc[1][0] += a1 * w0.x; acc[1][1] += a1 * w0.y; acc[1][2] += a1 * w0.z; acc[1][3] += a1 * w0.w;
      acc[1][4] += a1 * w1.x; acc[1][5] += a1 * w1.y; acc[1][6] += a1 * w1.z; acc[1][7] += a1 * w1.w;
    }
    __syncthreads();
  }
  float4* H4 = (float4*)h1;
  int g0 = gbase + 2 * ty, g1 = g0 + 1;
  H4[(size_t)g0 * 32 + tx * 2]     = make_float4(acc[0][0], acc[0][1], acc[0][2], acc[0][3]);
  H4[(size_t)g0 * 32 + tx * 2 + 1] = make_float4(acc[0][4], acc[0][5], acc[0][6], acc[0][7]);
  H4[(size_t)g1 * 32 + tx * 2]     = make_float4(acc[1][0], acc[1][1], acc[1][2], acc[1][3]);
  H4[(size_t)g1 * 32 + tx * 2 + 1] = make_float4(acc[1][4], acc[1][5], acc[1][6], acc[1][7]);
}

// ---------------- per-node attention scalars, layer 1 ----------------

__global__ __launch_bounds__(256) void k_alr1(const float* __restrict__ h1,
                                              const float* __restrict__ attl,
                                              const float* __restrict__ attr,
                                              float* __restrict__ al,
                                              float* __restrict__ ar) {
  int idx = blockIdx.x * 256 + threadIdx.x;
  if (idx >= N_NODES * 8) return;
  int n = idx >> 3, h = idx & 7;
  const float* hp = h1 + (size_t)n * 128 + h * 16;
  float sl = 0.f, sr = 0.f;
#pragma unroll
  for (int c = 0; c < 16; ++c) {
    float v = hp[c];
    sl += v * attl[h * 16 + c];
    sr += v * attr[h * 16 + c];
  }
  al[idx] = sl;
  ar[idx] = sr;
}

// ---------------- edge pass, layer 1 (wave per node) ----------------

__global__ __launch_bounds__(256) void k_edge1(const float* __restrict__ h1,
                                               const float* __restrict__ al,
                                               const float* __restrict__ ar,
                                               const int* __restrict__ rowptr,
                                               const int* __restrict__ csr,
                                               const float* __restrict__ b1,
                                               float* __restrict__ y1) {
  int wid = (blockIdx.x * 256 + threadIdx.x) >> 6;
  int lane = threadIdx.x & 63;
  if (wid >= N_NODES) return;
  int i = wid;
  int start = rowptr[i], end = rowptr[i + 1];
  const float2* H = (const float2*)h1;
  float2 hi = H[(size_t)i * 64 + lane];
  int hd = lane >> 3;  // head of this lane (channels 2*lane, 2*lane+1)
  float ar_i = ar[i * 8 + hd];
  float m = -INFINITY, s = 0.f, a0 = 0.f, a1 = 0.f;
  for (int e = start; e < end; ++e) {
    int j = __builtin_amdgcn_readfirstlane(csr[e]);
    float2 hj = H[(size_t)j * 64 + lane];
    float p = hi.x * hj.x + hi.y * hj.y;
    p += __shfl_xor(p, 1);
    p += __shfl_xor(p, 2);
    p += __shfl_xor(p, 4);            // per-head dot (8-lane groups)
    float alpha = al[j * 8 + hd] + ar_i;
    float sig = 1.f / (1.f + __expf(-p));
    alpha *= sig;
    alpha = alpha > 0.f ? alpha : NEG_SLOPE * alpha;
    float nm = fmaxf(m, alpha);
    float c1 = __expf(m - nm);
    float c2 = __expf(alpha - nm);
    s = s * c1 + c2;
    a0 = a0 * c1 + c2 * hj.x;
    a1 = a1 * c1 + c2 * hj.y;
    m = nm;
  }
  float inv = 1.f / s;
  float o0 = a0 * inv + b1[2 * lane];
  float o1 = a1 * inv + b1[2 * lane + 1];
  o0 = o0 > 0.f ? o0 : __expf(o0) - 1.f;  // ELU
  o1 = o1 > 0.f ? o1 : __expf(o1) - 1.f;
  ((float2*)y1)[(size_t)i * 64 + lane] = make_float2(o0, o1);
}

// ---------------- GEMM 2: h2 = y1 @ W2  [N,128]x[128,40] ----------------

__global__ __launch_bounds__(256) void k_gemm2(const float* __restrict__ y1,
                                               const float* __restrict__ W2,
                                               float* __restrict__ h2) {
  __shared__ float wsm[128 * 40];
  __shared__ float xsm[64 * 132];
  const int tid = threadIdx.x;
  const int tx = tid & 7;    // cols tx*5 .. tx*5+4
  const int ty = tid >> 3;   // 0..31 -> rows 2ty, 2ty+1
  const int gbase = blockIdx.x * 64;
  const float4* W4 = (const float4*)W2;   // 1280 float4
  const float4* Y4 = (const float4*)y1;
  float4* ws4 = (float4*)wsm;
  float4* xs4 = (float4*)xsm;             // row stride 33 float4
#pragma unroll
  for (int i = 0; i < 5; ++i) ws4[tid + i * 256] = W4[tid + i * 256];
#pragma unroll
  for (int i = 0; i < 8; ++i) {
    int l4 = tid + i * 256;               // 0..2047
    int r = l4 >> 5, c4 = l4 & 31;
    int g = gbase + r;
    float4 v = make_float4(0.f, 0.f, 0.f, 0.f);
    if (g < N_NODES) v = Y4[(size_t)g * 32 + c4];
    xs4[r * 33 + c4] = v;
  }
  __syncthreads();
  float acc[2][5] = {};
#pragma unroll 2
  for (int k = 0; k < 128; ++k) {
    float a0 = xsm[(2 * ty) * 132 + k];
    float a1 = xsm[(2 * ty + 1) * 132 + k];
#pragma unroll
    for (int c = 0; c < 5; ++c) {
      float w = wsm[k * 40 + tx * 5 + c];
      acc[0][c] += a0 * w;
      acc[1][c] += a1 * w;
    }
  }
  int g0 = gbase + 2 * ty, g1 = g0 + 1;
  if (g0 < N_NODES) {
#pragma unroll
    for (int c = 0; c < 5; ++c) h2[(size_t)g0 * 40 + tx * 5 + c] = acc[0][c];
  }
  if (g1 < N_NODES) {
#pragma unroll
    for (int c = 0; c < 5; ++c) h2[(size_t)g1 * 40 + tx * 5 + c] = acc[1][c];
  }
}

// ---------------- per-node attention scalars, layer 2 ----------------

__global__ __launch_bounds__(256) void k_alr2(const float* __restrict__ h2,
                                              const float* __restrict__ attl,
                                              const float* __restrict__ attr,
                                              float* __restrict__ al,
                                              float* __restrict__ ar) {
  int n = blockIdx.x * 256 + threadIdx.x;
  if (n >= N_NODES) return;
  float sl = 0.f, sr = 0.f;
#pragma unroll
  for (int c = 0; c < 40; ++c) {
    float v = h2[(size_t)n * 40 + c];
    sl += v * attl[c];
    sr += v * attr[c];
  }
  al[n] = sl;
  ar[n] = sr;
}

// ---------------- edge pass, layer 2 + log_softmax (wave per node) ----------------

__global__ __launch_bounds__(256) void k_edge2(const float* __restrict__ h2,
                                               const float* __restrict__ al,
                                               const float* __restrict__ ar,
                                               const int* __restrict__ rowptr,
                                               const int* __restrict__ csr,
                                               const float* __restrict__ b2,
                                               float* __restrict__ out) {
  int wid = (blockIdx.x * 256 + threadIdx.x) >> 6;
  int lane = threadIdx.x & 63;
  if (wid >= N_NODES) return;
  int i = wid;
  int start = rowptr[i], end = rowptr[i + 1];
  bool act = lane < 40;
  float hi = act ? h2[(size_t)i * 40 + lane] : 0.f;
  float ar_i = ar[i];
  float m = -INFINITY, s = 0.f, acc = 0.f;
  for (int e = start; e < end; ++e) {
    int j = __builtin_amdgcn_readfirstlane(csr[e]);
    float hj = act ? h2[(size_t)j * 40 + lane] : 0.f;
    float p = hi * hj;
    p += __shfl_xor(p, 1);
    p += __shfl_xor(p, 2);
    p += __shfl_xor(p, 4);
    p += __shfl_xor(p, 8);
    p += __shfl_xor(p, 16);
    p += __shfl_xor(p, 32);
    float alpha = al[j] + ar_i;
    float sig = 1.f / (1.f + __expf(-p));
    alpha *= sig;
    alpha = alpha > 0.f ? alpha : NEG_SLOPE * alpha;
    float nm = fmaxf(m, alpha);
    float c1 = __expf(m - nm);
    float c2 = __expf(alpha - nm);
    s = s * c1 + c2;
    acc = acc * c1 + c2 * hj;
    m = nm;
  }
  float o = acc / s + (act ? b2[lane] : 0.f);
  // log_softmax over the 40 classes (lanes >= 40 excluded)
  float v = act ? o : -INFINITY;
  float mx = v;
  mx = fmaxf(mx, __shfl_xor(mx, 1));
  mx = fmaxf(mx, __shfl_xor(mx, 2));
  mx = fmaxf(mx, __shfl_xor(mx, 4));
  mx = fmaxf(mx, __shfl_xor(mx, 8));
  mx = fmaxf(mx, __shfl_xor(mx, 16));
  mx = fmaxf(mx, __shfl_xor(mx, 32));
  float ex = act ? __expf(o - mx) : 0.f;
  float se = ex;
  se += __shfl_xor(se, 1);
  se += __shfl_xor(se, 2);
  se += __shfl_xor(se, 4);
  se += __shfl_xor(se, 8);
  se += __shfl_xor(se, 16);
  se += __shfl_xor(se, 32);
  float res = o - mx - __logf(se);
  if (act) out[(size_t)i * 40 + lane] = res;
}

// ---------------- launcher ----------------

extern "C" void kernel_launch(void* const* d_in, const int* in_sizes, int n_in,
                              void* d_out, int out_size, void* d_ws, size_t ws_size,
                              hipStream_t stream) {
  const float* x     = (const float*)d_in[0];
  const int*   ei    = (const int*)d_in[1];
  const float* W1    = (const float*)d_in[2];
  const float* attl1 = (const float*)d_in[3];
  const float* attr1 = (const float*)d_in[4];
  const float* b1    = (const float*)d_in[5];
  const float* W2    = (const float*)d_in[6];
  const float* attl2 = (const float*)d_in[7];
  const float* attr2 = (const float*)d_in[8];
  const float* b2    = (const float*)d_in[9];
  float* out = (float*)d_out;

  char* wsp = (char*)d_ws;
  size_t off = 0;
  auto alloc = [&](size_t bytes) {
    char* p = wsp + off;
    off = (off + bytes + 255) & ~(size_t)255;
    return p;
  };
  float* h1     = (float*)alloc((size_t)N_NODES * 128 * 4);
  float* y1     = (float*)alloc((size_t)N_NODES * 128 * 4);
  float* al1    = (float*)alloc((size_t)N_NODES * 8 * 4);
  float* ar1    = (float*)alloc((size_t)N_NODES * 8 * 4);
  int* deg      = (int*)alloc((size_t)N_NODES * 4);
  int* rowptr   = (int*)alloc((size_t)(N_NODES + 1) * 4);
  int* cursor   = (int*)alloc((size_t)N_NODES * 4);
  int* blocksum = (int*)alloc(128 * 4);
  int* blockoff = (int*)alloc(128 * 4);
  int* csr      = (int*)alloc((size_t)E2 * 4);
  float* h2  = h1;   // reuse: h1 dead after edge1
  float* al2 = al1;  // reuse: al1/ar1 dead after edge1
  float* ar2 = ar1;

  const int nb_scan = (N_NODES + 1023) / 1024;  // 98

  k_init<<<(N_NODES + 255) / 256, 256, 0, stream>>>(deg, cursor);
  k_hist<<<(N_EDGES + 255) / 256, 256, 0, stream>>>(ei, deg);
  k_scan1<<<nb_scan, 1024, 0, stream>>>(deg, rowptr, blocksum);
  k_scan2<<<1, 128, 0, stream>>>(blocksum, blockoff, nb_scan);
  k_scan3<<<nb_scan, 1024, 0, stream>>>(rowptr, blockoff);
  k_fill<<<(E2 + 255) / 256, 256, 0, stream>>>(ei, rowptr, cursor, csr);

  k_gemm1<<<N_NODES / 32, 256, 0, stream>>>(x, W1, h1);
  k_alr1<<<(N_NODES * 8 + 255) / 256, 256, 0, stream>>>(h1, attl1, attr1, al1, ar1);
  k_edge1<<<(N_NODES + 3) / 4, 256, 0, stream>>>(h1, al1, ar1, rowptr, csr, b1, y1);

  k_gemm2<<<(N_NODES + 63) / 64, 256, 0, stream>>>(y1, W2, h2);
  k_alr2<<<(N_NODES + 255) / 256, 256, 0, stream>>>(h2, attl2, attr2, al2, ar2);
  k_edge2<<<(N_NODES + 3) / 4, 256, 0, stream>>>(h2, al2, ar2, rowptr, csr, b2, out);
}

// Round 2
// 475.221 us; speedup vs baseline: 1.6010x; 1.6010x over previous
//
#include <hip/hip_runtime.h>
#include <math.h>

#define N_NODES 100000
#define N_EDGES 1600000
#define E2 (N_EDGES + N_NODES)
#define NEG_SLOPE 0.2f

typedef unsigned int uint;
typedef unsigned short ushort;

// ---------------- bf16 helpers ----------------

__device__ inline ushort f2bf(float x) {
  uint u = __float_as_uint(x);
  uint r = (u + 0x7FFFu + ((u >> 16) & 1u)) >> 16;   // RNE
  return (ushort)r;
}

__device__ inline uint pack2(float a, float b) {
  return (uint)f2bf(a) | ((uint)f2bf(b) << 16);
}

// unpack 8 bf16 (one uint4) -> 8 floats
__device__ inline void unpack8(uint4 q, float* f) {
  uint u[4] = {q.x, q.y, q.z, q.w};
#pragma unroll
  for (int k = 0; k < 4; ++k) {
    f[2 * k]     = __uint_as_float(u[k] << 16);
    f[2 * k + 1] = __uint_as_float(u[k] & 0xFFFF0000u);
  }
}

// ---------------- CSR construction ----------------

__global__ __launch_bounds__(256) void k_init(int* deg, int* cursor) {
  int i = blockIdx.x * 256 + threadIdx.x;
  if (i < N_NODES) { deg[i] = 1; cursor[i] = 0; }  // deg starts at 1: self-loop
}

__global__ __launch_bounds__(256) void k_hist(const int* __restrict__ ei, int* __restrict__ deg) {
  int e = blockIdx.x * 256 + threadIdx.x;
  if (e < N_EDGES) atomicAdd(&deg[ei[N_EDGES + e]], 1);
}

__global__ __launch_bounds__(1024) void k_scan1(const int* __restrict__ deg,
                                                int* __restrict__ rowptr,
                                                int* __restrict__ blocksum) {
  __shared__ int sm[1024];
  int idx = blockIdx.x * 1024 + threadIdx.x;
  int v = (idx < N_NODES) ? deg[idx] : 0;
  sm[threadIdx.x] = v;
  __syncthreads();
  for (int off = 1; off < 1024; off <<= 1) {
    int t = (threadIdx.x >= off) ? sm[threadIdx.x - off] : 0;
    __syncthreads();
    sm[threadIdx.x] += t;
    __syncthreads();
  }
  if (idx < N_NODES) rowptr[idx + 1] = sm[threadIdx.x];
  if (threadIdx.x == 1023) blocksum[blockIdx.x] = sm[1023];
}

__global__ __launch_bounds__(128) void k_scan2(const int* __restrict__ blocksum,
                                               int* __restrict__ blockoff, int nb) {
  __shared__ int sm[128];
  int v = (threadIdx.x < nb) ? blocksum[threadIdx.x] : 0;
  sm[threadIdx.x] = v;
  __syncthreads();
  for (int off = 1; off < 128; off <<= 1) {
    int t = (threadIdx.x >= off) ? sm[threadIdx.x - off] : 0;
    __syncthreads();
    sm[threadIdx.x] += t;
    __syncthreads();
  }
  if (threadIdx.x < nb) blockoff[threadIdx.x] = (threadIdx.x == 0) ? 0 : sm[threadIdx.x - 1];
}

__global__ __launch_bounds__(1024) void k_scan3(int* __restrict__ rowptr,
                                                const int* __restrict__ blockoff) {
  int idx = blockIdx.x * 1024 + threadIdx.x;
  if (idx < N_NODES) rowptr[idx + 1] += blockoff[blockIdx.x];
  if (idx == 0) rowptr[0] = 0;
}

__global__ __launch_bounds__(256) void k_fill(const int* __restrict__ ei,
                                              const int* __restrict__ rowptr,
                                              int* __restrict__ cursor,
                                              int* __restrict__ csr) {
  int e = blockIdx.x * 256 + threadIdx.x;
  if (e >= E2) return;
  int s, d;
  if (e < N_EDGES) { s = ei[e]; d = ei[N_EDGES + e]; }
  else { s = e - N_EDGES; d = s; }
  int pos = atomicAdd(&cursor[d], 1);
  csr[rowptr[d] + pos] = s;
}

// ---------------- GEMM 1: h1 = x @ W1  [N,128]x[128,128], bf16 out ----------------

__global__ __launch_bounds__(256) void k_gemm1(const float* __restrict__ x,
                                               const float* __restrict__ W1,
                                               ushort* __restrict__ h1b) {
  __shared__ float wsm[64 * 128];   // K-half of W: [64][128]
  __shared__ float xsm[32 * 68];    // x tile: [32 rows][64 k] pad->68
  const int tid = threadIdx.x;
  const int tx = tid & 15;          // col group: cols tx*8 .. tx*8+7
  const int ty = tid >> 4;          // 0..15 -> rows 2ty, 2ty+1
  const int gbase = blockIdx.x * 32;  // 3125*32 == 100000 exactly
  float acc[2][8] = {};
  const float4* W4 = (const float4*)W1;  // [128][32]
  const float4* X4 = (const float4*)x;   // [N][32]
  float4* ws4 = (float4*)wsm;
  float4* xs4 = (float4*)xsm;            // row stride 17 float4
  for (int p = 0; p < 2; ++p) {
#pragma unroll
    for (int i = 0; i < 8; ++i) {
      int l4 = tid + i * 256;            // 0..2047
      ws4[l4] = W4[p * 2048 + l4];
    }
#pragma unroll
    for (int i = 0; i < 2; ++i) {
      int l4 = tid + i * 256;            // 0..511
      int r = l4 >> 4, c4 = l4 & 15;
      xs4[r * 17 + c4] = X4[(size_t)(gbase + r) * 32 + p * 16 + c4];
    }
    __syncthreads();
#pragma unroll 4
    for (int k = 0; k < 64; ++k) {
      float a0 = xsm[(2 * ty) * 68 + k];
      float a1 = xsm[(2 * ty + 1) * 68 + k];
      float4 w0 = *(const float4*)&wsm[k * 128 + tx * 8];
      float4 w1 = *(const float4*)&wsm[k * 128 + tx * 8 + 4];
      acc[0][0] += a0 * w0.x; acc[0][1] += a0 * w0.y; acc[0][2] += a0 * w0.z; acc[0][3] += a0 * w0.w;
      acc[0][4] += a0 * w1.x; acc[0][5] += a0 * w1.y; acc[0][6] += a0 * w1.z; acc[0][7] += a0 * w1.w;
      acc[1][0] += a1 * w0.x; acc[1][1] += a1 * w0.y; acc[1][2] += a1 * w0.z; acc[1][3] += a1 * w0.w;
      acc[1][4] += a1 * w1.x; acc[1][5] += a1 * w1.y; acc[1][6] += a1 * w1.z; acc[1][7] += a1 * w1.w;
    }
    __syncthreads();
  }
  uint4* H1 = (uint4*)h1b;   // row = 128 bf16 = 16 uint4
  int g0 = gbase + 2 * ty, g1 = g0 + 1;
  uint4 o0, o1;
  o0.x = pack2(acc[0][0], acc[0][1]); o0.y = pack2(acc[0][2], acc[0][3]);
  o0.z = pack2(acc[0][4], acc[0][5]); o0.w = pack2(acc[0][6], acc[0][7]);
  o1.x = pack2(acc[1][0], acc[1][1]); o1.y = pack2(acc[1][2], acc[1][3]);
  o1.z = pack2(acc[1][4], acc[1][5]); o1.w = pack2(acc[1][6], acc[1][7]);
  H1[(size_t)g0 * 16 + tx] = o0;
  H1[(size_t)g1 * 16 + tx] = o1;
}

// ---------------- per-node attention scalars, layer 1 (bf16 h) ----------------

__global__ __launch_bounds__(256) void k_alr1(const ushort* __restrict__ h1b,
                                              const float* __restrict__ attl,
                                              const float* __restrict__ attr,
                                              float* __restrict__ al,
                                              float* __restrict__ ar) {
  int idx = blockIdx.x * 256 + threadIdx.x;
  if (idx >= N_NODES * 8) return;
  int n = idx >> 3, h = idx & 7;
  const uint4* H = (const uint4*)h1b;
  uint4 qa = H[(size_t)n * 16 + h * 2];
  uint4 qb = H[(size_t)n * 16 + h * 2 + 1];
  float f[16];
  unpack8(qa, f); unpack8(qb, f + 8);
  float sl = 0.f, sr = 0.f;
#pragma unroll
  for (int c = 0; c < 16; ++c) {
    sl += f[c] * attl[h * 16 + c];
    sr += f[c] * attr[h * 16 + c];
  }
  al[idx] = sl;
  ar[idx] = sr;
}

// ---------------- edge pass, layer 1: 4 edge-groups x 16 lanes x 8ch ----------------

__global__ __launch_bounds__(256) void k_edge1(const ushort* __restrict__ h1b,
                                               const float* __restrict__ al,
                                               const float* __restrict__ ar,
                                               const int* __restrict__ rowptr,
                                               const int* __restrict__ csr,
                                               const float* __restrict__ b1,
                                               float* __restrict__ y1) {
  int wid = (blockIdx.x * 256 + threadIdx.x) >> 6;
  int lane = threadIdx.x & 63;
  if (wid >= N_NODES) return;
  const int i = wid;
  const int l = lane & 15;   // channel slot: ch l*8 .. l*8+7
  const int g = lane >> 4;   // edge group 0..3
  const int h = l >> 1;      // head
  int start = rowptr[i], end = rowptr[i + 1];
  const uint4* H = (const uint4*)h1b;   // row = 16 uint4
  float hi[8];
  unpack8(H[(size_t)i * 16 + l], hi);
  float ar_i = ar[i * 8 + h];
  float s = 0.f;
  float acc[8] = {};
  for (int e = start + g; e < end; e += 4) {
    int j = csr[e];
    float hj[8];
    unpack8(H[(size_t)j * 16 + l], hj);
    float p = hi[0] * hj[0] + hi[1] * hj[1] + hi[2] * hj[2] + hi[3] * hj[3]
            + hi[4] * hj[4] + hi[5] * hj[5] + hi[6] * hj[6] + hi[7] * hj[7];
    p += __shfl_xor(p, 1);                      // per-head dot (lane pair)
    float a = al[j * 8 + h] + ar_i;
    a *= 1.f / (1.f + __expf(-p));              // * sigmoid(logit)
    a = a > 0.f ? a : NEG_SLOPE * a;            // leaky relu
    float ex = __expf(a);                       // no max-shift: |a| <~ 4, safe fp32
    s += ex;
#pragma unroll
    for (int c = 0; c < 8; ++c) acc[c] += ex * hj[c];
  }
  // merge the 4 edge groups (plain sums)
#pragma unroll
  for (int mask = 16; mask <= 32; mask <<= 1) {
    s += __shfl_xor(s, mask);
#pragma unroll
    for (int c = 0; c < 8; ++c) acc[c] += __shfl_xor(acc[c], mask);
  }
  if (g == 0) {
    float inv = 1.f / s;
    float4 r0, r1;
    float o[8];
#pragma unroll
    for (int c = 0; c < 8; ++c) {
      float v = acc[c] * inv + b1[l * 8 + c];
      o[c] = v > 0.f ? v : __expf(v) - 1.f;     // ELU
    }
    r0 = make_float4(o[0], o[1], o[2], o[3]);
    r1 = make_float4(o[4], o[5], o[6], o[7]);
    float4* Y = (float4*)y1;                    // row = 32 float4
    Y[(size_t)i * 32 + l * 2]     = r0;
    Y[(size_t)i * 32 + l * 2 + 1] = r1;
  }
}

// ---------------- GEMM 2: h2 = y1 @ W2  [N,128]x[128,40] -> bf16 padded [N,64] ----------------

__global__ __launch_bounds__(256) void k_gemm2(const float* __restrict__ y1,
                                               const float* __restrict__ W2,
                                               ushort* __restrict__ h2p) {
  __shared__ float wsm[128 * 40];
  __shared__ float xsm[64 * 132];
  const int tid = threadIdx.x;
  const int tx = tid & 7;    // cols tx*5 .. tx*5+4
  const int ty = tid >> 3;   // 0..31 -> rows 2ty, 2ty+1
  const int gbase = blockIdx.x * 64;
  const float4* W4 = (const float4*)W2;   // 1280 float4
  const float4* Y4 = (const float4*)y1;
  float4* ws4 = (float4*)wsm;
  float4* xs4 = (float4*)xsm;             // row stride 33 float4
#pragma unroll
  for (int i = 0; i < 5; ++i) ws4[tid + i * 256] = W4[tid + i * 256];
#pragma unroll
  for (int i = 0; i < 8; ++i) {
    int l4 = tid + i * 256;               // 0..2047
    int r = l4 >> 5, c4 = l4 & 31;
    int g = gbase + r;
    float4 v = make_float4(0.f, 0.f, 0.f, 0.f);
    if (g < N_NODES) v = Y4[(size_t)g * 32 + c4];
    xs4[r * 33 + c4] = v;
  }
  __syncthreads();
  float acc[2][5] = {};
#pragma unroll 2
  for (int k = 0; k < 128; ++k) {
    float a0 = xsm[(2 * ty) * 132 + k];
    float a1 = xsm[(2 * ty + 1) * 132 + k];
#pragma unroll
    for (int c = 0; c < 5; ++c) {
      float w = wsm[k * 40 + tx * 5 + c];
      acc[0][c] += a0 * w;
      acc[1][c] += a1 * w;
    }
  }
  int g0 = gbase + 2 * ty, g1 = g0 + 1;
  if (g0 < N_NODES) {
#pragma unroll
    for (int c = 0; c < 5; ++c) h2p[(size_t)g0 * 64 + tx * 5 + c] = f2bf(acc[0][c]);
#pragma unroll
    for (int c = 0; c < 3; ++c) h2p[(size_t)g0 * 64 + 40 + tx * 3 + c] = 0;  // zero pads
  }
  if (g1 < N_NODES) {
#pragma unroll
    for (int c = 0; c < 5; ++c) h2p[(size_t)g1 * 64 + tx * 5 + c] = f2bf(acc[1][c]);
#pragma unroll
    for (int c = 0; c < 3; ++c) h2p[(size_t)g1 * 64 + 40 + tx * 3 + c] = 0;
  }
}

// ---------------- per-node attention scalars, layer 2 (bf16 padded h2) ----------------

__global__ __launch_bounds__(256) void k_alr2(const ushort* __restrict__ h2p,
                                              const float* __restrict__ attl,
                                              const float* __restrict__ attr,
                                              float* __restrict__ al,
                                              float* __restrict__ ar) {
  int n = blockIdx.x * 256 + threadIdx.x;
  if (n >= N_NODES) return;
  const uint4* H = (const uint4*)h2p;   // row = 8 uint4 (64 ch)
  float sl = 0.f, sr = 0.f;
#pragma unroll
  for (int q = 0; q < 5; ++q) {
    float f[8];
    unpack8(H[(size_t)n * 8 + q], f);
#pragma unroll
    for (int k = 0; k < 8; ++k) {
      sl += f[k] * attl[q * 8 + k];
      sr += f[k] * attr[q * 8 + k];
    }
  }
  al[n] = sl;
  ar[n] = sr;
}

// ---------------- edge pass, layer 2: 8 edge-groups x 8 lanes x 8ch + log_softmax ----------------

__global__ __launch_bounds__(256) void k_edge2(const ushort* __restrict__ h2p,
                                               const float* __restrict__ al,
                                               const float* __restrict__ ar,
                                               const int* __restrict__ rowptr,
                                               const int* __restrict__ csr,
                                               const float* __restrict__ b2,
                                               float* __restrict__ out) {
  int wid = (blockIdx.x * 256 + threadIdx.x) >> 6;
  int lane = threadIdx.x & 63;
  if (wid >= N_NODES) return;
  const int i = wid;
  const int l = lane & 7;    // channel slot: ch l*8 .. l*8+7 (pads >= 40 are zero)
  const int g = lane >> 3;   // edge group 0..7
  int start = rowptr[i], end = rowptr[i + 1];
  const uint4* H = (const uint4*)h2p;   // row = 8 uint4
  float hi[8];
  unpack8(H[(size_t)i * 8 + l], hi);
  float ar_i = ar[i];
  float s = 0.f;
  float acc[8] = {};
  for (int e = start + g; e < end; e += 8) {
    int j = csr[e];
    float hj[8];
    unpack8(H[(size_t)j * 8 + l], hj);
    float p = hi[0] * hj[0] + hi[1] * hj[1] + hi[2] * hj[2] + hi[3] * hj[3]
            + hi[4] * hj[4] + hi[5] * hj[5] + hi[6] * hj[6] + hi[7] * hj[7];
    p += __shfl_xor(p, 1);
    p += __shfl_xor(p, 2);
    p += __shfl_xor(p, 4);                      // dot over 64 (pads contribute 0)
    float a = al[j] + ar_i;
    a *= 1.f / (1.f + __expf(-p));
    a = a > 0.f ? a : NEG_SLOPE * a;
    float ex = __expf(a);
    s += ex;
#pragma unroll
    for (int c = 0; c < 8; ++c) acc[c] += ex * hj[c];
  }
  // merge 8 edge groups
#pragma unroll
  for (int mask = 8; mask <= 32; mask <<= 1) {
    s += __shfl_xor(s, mask);
#pragma unroll
    for (int c = 0; c < 8; ++c) acc[c] += __shfl_xor(acc[c], mask);
  }
  // epilogue: bias + log_softmax over 40 classes (lanes l<5 hold valid channels)
  float inv = 1.f / s;
  bool act = l < 5;
  float o[8];
  float mx = -1e30f;
#pragma unroll
  for (int c = 0; c < 8; ++c) {
    float b = act ? b2[l * 8 + c] : 0.f;
    o[c] = acc[c] * inv + b;
    if (act) mx = fmaxf(mx, o[c]);
  }
  mx = fmaxf(mx, __shfl_xor(mx, 1));
  mx = fmaxf(mx, __shfl_xor(mx, 2));
  mx = fmaxf(mx, __shfl_xor(mx, 4));
  float se = 0.f;
  if (act) {
#pragma unroll
    for (int c = 0; c < 8; ++c) se += __expf(o[c] - mx);
  }
  se += __shfl_xor(se, 1);
  se += __shfl_xor(se, 2);
  se += __shfl_xor(se, 4);
  if (g == 0 && act) {
    float lse = mx + __logf(se);
    float4 r0 = make_float4(o[0] - lse, o[1] - lse, o[2] - lse, o[3] - lse);
    float4 r1 = make_float4(o[4] - lse, o[5] - lse, o[6] - lse, o[7] - lse);
    float4* O = (float4*)(out + (size_t)i * 40 + l * 8);
    O[0] = r0;
    O[1] = r1;
  }
}

// ---------------- launcher ----------------

extern "C" void kernel_launch(void* const* d_in, const int* in_sizes, int n_in,
                              void* d_out, int out_size, void* d_ws, size_t ws_size,
                              hipStream_t stream) {
  const float* x     = (const float*)d_in[0];
  const int*   ei    = (const int*)d_in[1];
  const float* W1    = (const float*)d_in[2];
  const float* attl1 = (const float*)d_in[3];
  const float* attr1 = (const float*)d_in[4];
  const float* b1    = (const float*)d_in[5];
  const float* W2    = (const float*)d_in[6];
  const float* attl2 = (const float*)d_in[7];
  const float* attr2 = (const float*)d_in[8];
  const float* b2    = (const float*)d_in[9];
  float* out = (float*)d_out;

  char* wsp = (char*)d_ws;
  size_t off = 0;
  auto alloc = [&](size_t bytes) {
    char* p = wsp + off;
    off = (off + bytes + 255) & ~(size_t)255;
    return p;
  };
  ushort* h1b   = (ushort*)alloc((size_t)N_NODES * 128 * 2);  // bf16 h1
  float* y1     = (float*)alloc((size_t)N_NODES * 128 * 4);
  float* al1    = (float*)alloc((size_t)N_NODES * 8 * 4);
  float* ar1    = (float*)alloc((size_t)N_NODES * 8 * 4);
  int* deg      = (int*)alloc((size_t)N_NODES * 4);
  int* rowptr   = (int*)alloc((size_t)(N_NODES + 1) * 4);
  int* cursor   = (int*)alloc((size_t)N_NODES * 4);
  int* blocksum = (int*)alloc(128 * 4);
  int* blockoff = (int*)alloc(128 * 4);
  int* csr      = (int*)alloc((size_t)E2 * 4);
  ushort* h2p = h1b;   // reuse: h1b dead after edge1 ([N,64] bf16 <= [N,128] bf16)
  float* al2  = al1;   // reuse: al1/ar1 dead after edge1
  float* ar2  = ar1;

  const int nb_scan = (N_NODES + 1023) / 1024;  // 98

  k_init<<<(N_NODES + 255) / 256, 256, 0, stream>>>(deg, cursor);
  k_hist<<<(N_EDGES + 255) / 256, 256, 0, stream>>>(ei, deg);
  k_scan1<<<nb_scan, 1024, 0, stream>>>(deg, rowptr, blocksum);
  k_scan2<<<1, 128, 0, stream>>>(blocksum, blockoff, nb_scan);
  k_scan3<<<nb_scan, 1024, 0, stream>>>(rowptr, blockoff);
  k_fill<<<(E2 + 255) / 256, 256, 0, stream>>>(ei, rowptr, cursor, csr);

  k_gemm1<<<N_NODES / 32, 256, 0, stream>>>(x, W1, h1b);
  k_alr1<<<(N_NODES * 8 + 255) / 256, 256, 0, stream>>>(h1b, attl1, attr1, al1, ar1);
  k_edge1<<<(N_NODES + 3) / 4, 256, 0, stream>>>(h1b, al1, ar1, rowptr, csr, b1, y1);

  k_gemm2<<<(N_NODES + 63) / 64, 256, 0, stream>>>(y1, W2, h2p);
  k_alr2<<<(N_NODES + 255) / 256, 256, 0, stream>>>(h2p, attl2, attr2, al2, ar2);
  k_edge2<<<(N_NODES + 3) / 4, 256, 0, stream>>>(h2p, al2, ar2, rowptr, csr, b2, out);
}

// Round 3
// 343.368 us; speedup vs baseline: 2.2158x; 1.3840x over previous
//
#include <hip/hip_runtime.h>
#include <math.h>

#define N_NODES 100000
#define N_EDGES 1600000
#define E2 (N_EDGES + N_NODES)
#define NEG_SLOPE 0.2f

#define NPB 256                      // nodes per bucket
#define NB  ((N_NODES + NPB - 1) / NPB)   // 391 buckets
#define CAP 4800                     // per-bucket edge capacity (mean 4352, +6 sigma)
#define BCH 8192                     // edges per block in k_bucket

typedef unsigned int uint;
typedef unsigned short ushort;

// ---------------- bf16 helpers ----------------

__device__ inline ushort f2bf(float x) {
  uint u = __float_as_uint(x);
  uint r = (u + 0x7FFFu + ((u >> 16) & 1u)) >> 16;   // RNE
  return (ushort)r;
}

__device__ inline uint pack2(float a, float b) {
  return (uint)f2bf(a) | ((uint)f2bf(b) << 16);
}

// unpack 8 bf16 (one uint4) -> 8 floats
__device__ inline void unpack8(uint4 q, float* f) {
  uint u[4] = {q.x, q.y, q.z, q.w};
#pragma unroll
  for (int k = 0; k < 4; ++k) {
    f[2 * k]     = __uint_as_float(u[k] << 16);
    f[2 * k + 1] = __uint_as_float(u[k] & 0xFFFF0000u);
  }
}

// ---------------- bucketed CSR construction ----------------

__global__ __launch_bounds__(512) void k_init0(int* bcursor) {
  int t = threadIdx.x;
  if (t < NB) bcursor[t] = t * CAP;
}

// Pass A: scatter packed edges into per-bucket append regions.
__global__ __launch_bounds__(256) void k_bucket(const int* __restrict__ ei,
                                                int* __restrict__ bcursor,
                                                uint* __restrict__ pbuf) {
  __shared__ int cnt[NB];
  __shared__ int base[NB];
  const int tid = threadIdx.x;
  const int ebase = blockIdx.x * BCH;
  for (int t = tid; t < NB; t += 256) cnt[t] = 0;
  __syncthreads();
  // phase 1: count
#pragma unroll 4
  for (int k = 0; k < BCH / 256; ++k) {
    int e = ebase + tid + k * 256;
    if (e < E2) {
      int d = (e < N_EDGES) ? ei[N_EDGES + e] : (e - N_EDGES);
      atomicAdd(&cnt[d >> 8], 1);
    }
  }
  __syncthreads();
  // phase 2: reserve global space, reset local cursors
  for (int t = tid; t < NB; t += 256) {
    int c = cnt[t];
    base[t] = c ? atomicAdd(&bcursor[t], c) : 0;
    cnt[t] = 0;
  }
  __syncthreads();
  // phase 3: scatter
#pragma unroll 4
  for (int k = 0; k < BCH / 256; ++k) {
    int e = ebase + tid + k * 256;
    if (e < E2) {
      int s, d;
      if (e < N_EDGES) { s = ei[e]; d = ei[N_EDGES + e]; }
      else { s = e - N_EDGES; d = s; }
      int b = d >> 8;
      int pos = base[b] + atomicAdd(&cnt[b], 1);
      pbuf[pos] = ((uint)s << 8) | (uint)(d & 255);
    }
  }
}

// tiny scan over bucket totals -> bucket base offsets in final CSR
__global__ __launch_bounds__(512) void k_scanB(const int* __restrict__ bcursor,
                                               int* __restrict__ bbase,
                                               int* __restrict__ rowptr) {
  __shared__ int sm[512];
  int t = threadIdx.x;
  int v = (t < NB) ? (bcursor[t] - t * CAP) : 0;
  sm[t] = v;
  __syncthreads();
  for (int off = 1; off < 512; off <<= 1) {
    int u = (t >= off) ? sm[t - off] : 0;
    __syncthreads();
    sm[t] += u;
    __syncthreads();
  }
  if (t < NB) bbase[t] = sm[t] - v;   // exclusive
  if (t == 0) rowptr[N_NODES] = E2;
}

// Pass B: per-bucket CSR segment build in LDS + rowptr emit.
__global__ __launch_bounds__(256) void k_csr(const uint* __restrict__ pbuf,
                                             const int* __restrict__ bcursor,
                                             const int* __restrict__ bbase,
                                             int* __restrict__ rowptr,
                                             int* __restrict__ csr) {
  __shared__ int hist[NPB];
  __shared__ int excl[NPB];
  __shared__ int cur[NPB];
  __shared__ int lcsr[CAP];
  const int b = blockIdx.x;
  const int tid = threadIdx.x;
  int count = bcursor[b] - b * CAP;
  if (count > CAP) count = CAP;
  const int gbase = bbase[b];
  const uint* seg = pbuf + b * CAP;
  hist[tid] = 0;
  __syncthreads();
  for (int k = tid; k < count; k += 256) atomicAdd(&hist[seg[k] & 255u], 1);
  __syncthreads();
  // exclusive scan of hist (Hillis-Steele on 256)
  int own = hist[tid];
  excl[tid] = own;
  __syncthreads();
  for (int off = 1; off < 256; off <<= 1) {
    int u = (tid >= off) ? excl[tid - off] : 0;
    __syncthreads();
    excl[tid] += u;
    __syncthreads();
  }
  int ex = excl[tid] - own;
  cur[tid] = ex;
  int node = b * NPB + tid;
  if (node < N_NODES) rowptr[node] = gbase + ex;
  __syncthreads();
  // scatter into LDS segment
  for (int k = tid; k < count; k += 256) {
    uint pk = seg[k];
    int nd = pk & 255u;
    int pos = atomicAdd(&cur[nd], 1);
    lcsr[pos] = (int)(pk >> 8);
  }
  __syncthreads();
  // coalesced write-out
  for (int k = tid; k < count; k += 256) csr[gbase + k] = lcsr[k];
}

// ---------------- GEMM 1: h1 = x @ W1  [N,128]x[128,128], bf16 out ----------------

__global__ __launch_bounds__(256) void k_gemm1(const float* __restrict__ x,
                                               const float* __restrict__ W1,
                                               ushort* __restrict__ h1b) {
  __shared__ float wsm[64 * 128];   // K-half of W: [64][128]
  __shared__ float xsm[32 * 68];    // x tile: [32 rows][64 k] pad->68
  const int tid = threadIdx.x;
  const int tx = tid & 15;          // col group: cols tx*8 .. tx*8+7
  const int ty = tid >> 4;          // 0..15 -> rows 2ty, 2ty+1
  const int gbase = blockIdx.x * 32;  // 3125*32 == 100000 exactly
  float acc[2][8] = {};
  const float4* W4 = (const float4*)W1;  // [128][32]
  const float4* X4 = (const float4*)x;   // [N][32]
  float4* ws4 = (float4*)wsm;
  float4* xs4 = (float4*)xsm;            // row stride 17 float4
  for (int p = 0; p < 2; ++p) {
#pragma unroll
    for (int i = 0; i < 8; ++i) {
      int l4 = tid + i * 256;            // 0..2047
      ws4[l4] = W4[p * 2048 + l4];
    }
#pragma unroll
    for (int i = 0; i < 2; ++i) {
      int l4 = tid + i * 256;            // 0..511
      int r = l4 >> 4, c4 = l4 & 15;
      xs4[r * 17 + c4] = X4[(size_t)(gbase + r) * 32 + p * 16 + c4];
    }
    __syncthreads();
#pragma unroll 4
    for (int k = 0; k < 64; ++k) {
      float a0 = xsm[(2 * ty) * 68 + k];
      float a1 = xsm[(2 * ty + 1) * 68 + k];
      float4 w0 = *(const float4*)&wsm[k * 128 + tx * 8];
      float4 w1 = *(const float4*)&wsm[k * 128 + tx * 8 + 4];
      acc[0][0] += a0 * w0.x; acc[0][1] += a0 * w0.y; acc[0][2] += a0 * w0.z; acc[0][3] += a0 * w0.w;
      acc[0][4] += a0 * w1.x; acc[0][5] += a0 * w1.y; acc[0][6] += a0 * w1.z; acc[0][7] += a0 * w1.w;
      acc[1][0] += a1 * w0.x; acc[1][1] += a1 * w0.y; acc[1][2] += a1 * w0.z; acc[1][3] += a1 * w0.w;
      acc[1][4] += a1 * w1.x; acc[1][5] += a1 * w1.y; acc[1][6] += a1 * w1.z; acc[1][7] += a1 * w1.w;
    }
    __syncthreads();
  }
  uint4* H1 = (uint4*)h1b;   // row = 128 bf16 = 16 uint4
  int g0 = gbase + 2 * ty, g1 = g0 + 1;
  uint4 o0, o1;
  o0.x = pack2(acc[0][0], acc[0][1]); o0.y = pack2(acc[0][2], acc[0][3]);
  o0.z = pack2(acc[0][4], acc[0][5]); o0.w = pack2(acc[0][6], acc[0][7]);
  o1.x = pack2(acc[1][0], acc[1][1]); o1.y = pack2(acc[1][2], acc[1][3]);
  o1.z = pack2(acc[1][4], acc[1][5]); o1.w = pack2(acc[1][6], acc[1][7]);
  H1[(size_t)g0 * 16 + tx] = o0;
  H1[(size_t)g1 * 16 + tx] = o1;
}

// ---------------- per-node attention scalars, layer 1 (bf16 h) ----------------

__global__ __launch_bounds__(256) void k_alr1(const ushort* __restrict__ h1b,
                                              const float* __restrict__ attl,
                                              const float* __restrict__ attr,
                                              float* __restrict__ al,
                                              float* __restrict__ ar) {
  int idx = blockIdx.x * 256 + threadIdx.x;
  if (idx >= N_NODES * 8) return;
  int n = idx >> 3, h = idx & 7;
  const uint4* H = (const uint4*)h1b;
  uint4 qa = H[(size_t)n * 16 + h * 2];
  uint4 qb = H[(size_t)n * 16 + h * 2 + 1];
  float f[16];
  unpack8(qa, f); unpack8(qb, f + 8);
  float sl = 0.f, sr = 0.f;
#pragma unroll
  for (int c = 0; c < 16; ++c) {
    sl += f[c] * attl[h * 16 + c];
    sr += f[c] * attr[h * 16 + c];
  }
  al[idx] = sl;
  ar[idx] = sr;
}

// ---------------- edge pass, layer 1: 4 edge-groups x 16 lanes x 8ch ----------------

__global__ __launch_bounds__(256) void k_edge1(const ushort* __restrict__ h1b,
                                               const float* __restrict__ al,
                                               const float* __restrict__ ar,
                                               const int* __restrict__ rowptr,
                                               const int* __restrict__ csr,
                                               const float* __restrict__ b1,
                                               float* __restrict__ y1) {
  int wid = (blockIdx.x * 256 + threadIdx.x) >> 6;
  int lane = threadIdx.x & 63;
  if (wid >= N_NODES) return;
  const int i = wid;
  const int l = lane & 15;   // channel slot: ch l*8 .. l*8+7
  const int g = lane >> 4;   // edge group 0..3
  const int h = l >> 1;      // head
  int start = rowptr[i], end = rowptr[i + 1];
  const uint4* H = (const uint4*)h1b;   // row = 16 uint4
  float hi[8];
  unpack8(H[(size_t)i * 16 + l], hi);
  float ar_i = ar[i * 8 + h];
  float s = 0.f;
  float acc[8] = {};
  for (int e = start + g; e < end; e += 4) {
    int j = csr[e];
    float hj[8];
    unpack8(H[(size_t)j * 16 + l], hj);
    float p = hi[0] * hj[0] + hi[1] * hj[1] + hi[2] * hj[2] + hi[3] * hj[3]
            + hi[4] * hj[4] + hi[5] * hj[5] + hi[6] * hj[6] + hi[7] * hj[7];
    p += __shfl_xor(p, 1);                      // per-head dot (lane pair)
    float a = al[j * 8 + h] + ar_i;
    a *= 1.f / (1.f + __expf(-p));              // * sigmoid(logit)
    a = a > 0.f ? a : NEG_SLOPE * a;            // leaky relu
    float ex = __expf(a);                       // no max-shift: |a| <~ 4, safe fp32
    s += ex;
#pragma unroll
    for (int c = 0; c < 8; ++c) acc[c] += ex * hj[c];
  }
  // merge the 4 edge groups (plain sums)
#pragma unroll
  for (int mask = 16; mask <= 32; mask <<= 1) {
    s += __shfl_xor(s, mask);
#pragma unroll
    for (int c = 0; c < 8; ++c) acc[c] += __shfl_xor(acc[c], mask);
  }
  if (g == 0) {
    float inv = 1.f / s;
    float4 r0, r1;
    float o[8];
#pragma unroll
    for (int c = 0; c < 8; ++c) {
      float v = acc[c] * inv + b1[l * 8 + c];
      o[c] = v > 0.f ? v : __expf(v) - 1.f;     // ELU
    }
    r0 = make_float4(o[0], o[1], o[2], o[3]);
    r1 = make_float4(o[4], o[5], o[6], o[7]);
    float4* Y = (float4*)y1;                    // row = 32 float4
    Y[(size_t)i * 32 + l * 2]     = r0;
    Y[(size_t)i * 32 + l * 2 + 1] = r1;
  }
}

// ---------------- GEMM 2: h2 = y1 @ W2  [N,128]x[128,40] -> bf16 padded [N,64] ----------------

__global__ __launch_bounds__(256) void k_gemm2(const float* __restrict__ y1,
                                               const float* __restrict__ W2,
                                               ushort* __restrict__ h2p) {
  __shared__ float wsm[128 * 40];
  __shared__ float xsm[64 * 132];
  const int tid = threadIdx.x;
  const int tx = tid & 7;    // cols tx*5 .. tx*5+4
  const int ty = tid >> 3;   // 0..31 -> rows 2ty, 2ty+1
  const int gbase = blockIdx.x * 64;
  const float4* W4 = (const float4*)W2;   // 1280 float4
  const float4* Y4 = (const float4*)y1;
  float4* ws4 = (float4*)wsm;
  float4* xs4 = (float4*)xsm;             // row stride 33 float4
#pragma unroll
  for (int i = 0; i < 5; ++i) ws4[tid + i * 256] = W4[tid + i * 256];
#pragma unroll
  for (int i = 0; i < 8; ++i) {
    int l4 = tid + i * 256;               // 0..2047
    int r = l4 >> 5, c4 = l4 & 31;
    int g = gbase + r;
    float4 v = make_float4(0.f, 0.f, 0.f, 0.f);
    if (g < N_NODES) v = Y4[(size_t)g * 32 + c4];
    xs4[r * 33 + c4] = v;
  }
  __syncthreads();
  float acc[2][5] = {};
#pragma unroll 2
  for (int k = 0; k < 128; ++k) {
    float a0 = xsm[(2 * ty) * 132 + k];
    float a1 = xsm[(2 * ty + 1) * 132 + k];
#pragma unroll
    for (int c = 0; c < 5; ++c) {
      float w = wsm[k * 40 + tx * 5 + c];
      acc[0][c] += a0 * w;
      acc[1][c] += a1 * w;
    }
  }
  int g0 = gbase + 2 * ty, g1 = g0 + 1;
  if (g0 < N_NODES) {
#pragma unroll
    for (int c = 0; c < 5; ++c) h2p[(size_t)g0 * 64 + tx * 5 + c] = f2bf(acc[0][c]);
#pragma unroll
    for (int c = 0; c < 3; ++c) h2p[(size_t)g0 * 64 + 40 + tx * 3 + c] = 0;  // zero pads
  }
  if (g1 < N_NODES) {
#pragma unroll
    for (int c = 0; c < 5; ++c) h2p[(size_t)g1 * 64 + tx * 5 + c] = f2bf(acc[1][c]);
#pragma unroll
    for (int c = 0; c < 3; ++c) h2p[(size_t)g1 * 64 + 40 + tx * 3 + c] = 0;
  }
}

// ---------------- per-node attention scalars, layer 2 (bf16 padded h2) ----------------

__global__ __launch_bounds__(256) void k_alr2(const ushort* __restrict__ h2p,
                                              const float* __restrict__ attl,
                                              const float* __restrict__ attr,
                                              float* __restrict__ al,
                                              float* __restrict__ ar) {
  int n = blockIdx.x * 256 + threadIdx.x;
  if (n >= N_NODES) return;
  const uint4* H = (const uint4*)h2p;   // row = 8 uint4 (64 ch)
  float sl = 0.f, sr = 0.f;
#pragma unroll
  for (int q = 0; q < 5; ++q) {
    float f[8];
    unpack8(H[(size_t)n * 8 + q], f);
#pragma unroll
    for (int k = 0; k < 8; ++k) {
      sl += f[k] * attl[q * 8 + k];
      sr += f[k] * attr[q * 8 + k];
    }
  }
  al[n] = sl;
  ar[n] = sr;
}

// ---------------- edge pass, layer 2: 8 edge-groups x 8 lanes x 8ch + log_softmax ----------------

__global__ __launch_bounds__(256) void k_edge2(const ushort* __restrict__ h2p,
                                               const float* __restrict__ al,
                                               const float* __restrict__ ar,
                                               const int* __restrict__ rowptr,
                                               const int* __restrict__ csr,
                                               const float* __restrict__ b2,
                                               float* __restrict__ out) {
  int wid = (blockIdx.x * 256 + threadIdx.x) >> 6;
  int lane = threadIdx.x & 63;
  if (wid >= N_NODES) return;
  const int i = wid;
  const int l = lane & 7;    // channel slot: ch l*8 .. l*8+7 (pads >= 40 are zero)
  const int g = lane >> 3;   // edge group 0..7
  int start = rowptr[i], end = rowptr[i + 1];
  const uint4* H = (const uint4*)h2p;   // row = 8 uint4
  float hi[8];
  unpack8(H[(size_t)i * 8 + l], hi);
  float ar_i = ar[i];
  float s = 0.f;
  float acc[8] = {};
  for (int e = start + g; e < end; e += 8) {
    int j = csr[e];
    float hj[8];
    unpack8(H[(size_t)j * 8 + l], hj);
    float p = hi[0] * hj[0] + hi[1] * hj[1] + hi[2] * hj[2] + hi[3] * hj[3]
            + hi[4] * hj[4] + hi[5] * hj[5] + hi[6] * hj[6] + hi[7] * hj[7];
    p += __shfl_xor(p, 1);
    p += __shfl_xor(p, 2);
    p += __shfl_xor(p, 4);                      // dot over 64 (pads contribute 0)
    float a = al[j] + ar_i;
    a *= 1.f / (1.f + __expf(-p));
    a = a > 0.f ? a : NEG_SLOPE * a;
    float ex = __expf(a);
    s += ex;
#pragma unroll
    for (int c = 0; c < 8; ++c) acc[c] += ex * hj[c];
  }
  // merge 8 edge groups
#pragma unroll
  for (int mask = 8; mask <= 32; mask <<= 1) {
    s += __shfl_xor(s, mask);
#pragma unroll
    for (int c = 0; c < 8; ++c) acc[c] += __shfl_xor(acc[c], mask);
  }
  // epilogue: bias + log_softmax over 40 classes (lanes l<5 hold valid channels)
  float inv = 1.f / s;
  bool act = l < 5;
  float o[8];
  float mx = -1e30f;
#pragma unroll
  for (int c = 0; c < 8; ++c) {
    float b = act ? b2[l * 8 + c] : 0.f;
    o[c] = acc[c] * inv + b;
    if (act) mx = fmaxf(mx, o[c]);
  }
  mx = fmaxf(mx, __shfl_xor(mx, 1));
  mx = fmaxf(mx, __shfl_xor(mx, 2));
  mx = fmaxf(mx, __shfl_xor(mx, 4));
  float se = 0.f;
  if (act) {
#pragma unroll
    for (int c = 0; c < 8; ++c) se += __expf(o[c] - mx);
  }
  se += __shfl_xor(se, 1);
  se += __shfl_xor(se, 2);
  se += __shfl_xor(se, 4);
  if (g == 0 && act) {
    float lse = mx + __logf(se);
    float4 r0 = make_float4(o[0] - lse, o[1] - lse, o[2] - lse, o[3] - lse);
    float4 r1 = make_float4(o[4] - lse, o[5] - lse, o[6] - lse, o[7] - lse);
    float4* O = (float4*)(out + (size_t)i * 40 + l * 8);
    O[0] = r0;
    O[1] = r1;
  }
}

// ---------------- launcher ----------------

extern "C" void kernel_launch(void* const* d_in, const int* in_sizes, int n_in,
                              void* d_out, int out_size, void* d_ws, size_t ws_size,
                              hipStream_t stream) {
  const float* x     = (const float*)d_in[0];
  const int*   ei    = (const int*)d_in[1];
  const float* W1    = (const float*)d_in[2];
  const float* attl1 = (const float*)d_in[3];
  const float* attr1 = (const float*)d_in[4];
  const float* b1    = (const float*)d_in[5];
  const float* W2    = (const float*)d_in[6];
  const float* attl2 = (const float*)d_in[7];
  const float* attr2 = (const float*)d_in[8];
  const float* b2    = (const float*)d_in[9];
  float* out = (float*)d_out;

  char* wsp = (char*)d_ws;
  size_t off = 0;
  auto alloc = [&](size_t bytes) {
    char* p = wsp + off;
    off = (off + bytes + 255) & ~(size_t)255;
    return p;
  };
  ushort* h1b   = (ushort*)alloc((size_t)N_NODES * 128 * 2);  // bf16 h1
  float* y1     = (float*)alloc((size_t)N_NODES * 128 * 4);
  float* al1    = (float*)alloc((size_t)N_NODES * 8 * 4);
  float* ar1    = (float*)alloc((size_t)N_NODES * 8 * 4);
  int* rowptr   = (int*)alloc((size_t)(N_NODES + 1) * 4);
  int* bcursor  = (int*)alloc((size_t)NB * 4);
  int* bbase    = (int*)alloc((size_t)NB * 4);
  int* csr      = (int*)alloc((size_t)E2 * 4);
  uint* pbuf  = (uint*)y1;   // overlay: pbuf dead before edge1 writes y1
  ushort* h2p = h1b;         // reuse: h1b dead after edge1
  float* al2  = al1;         // reuse: al1/ar1 dead after edge1
  float* ar2  = ar1;

  // CSR build (bucketed two-pass)
  k_init0<<<1, 512, 0, stream>>>(bcursor);
  k_bucket<<<(E2 + BCH - 1) / BCH, 256, 0, stream>>>(ei, bcursor, pbuf);
  k_scanB<<<1, 512, 0, stream>>>(bcursor, bbase, rowptr);
  k_csr<<<NB, 256, 0, stream>>>(pbuf, bcursor, bbase, rowptr, csr);

  k_gemm1<<<N_NODES / 32, 256, 0, stream>>>(x, W1, h1b);
  k_alr1<<<(N_NODES * 8 + 255) / 256, 256, 0, stream>>>(h1b, attl1, attr1, al1, ar1);
  k_edge1<<<(N_NODES + 3) / 4, 256, 0, stream>>>(h1b, al1, ar1, rowptr, csr, b1, y1);

  k_gemm2<<<(N_NODES + 63) / 64, 256, 0, stream>>>(y1, W2, h2p);
  k_alr2<<<(N_NODES + 255) / 256, 256, 0, stream>>>(h2p, attl2, attr2, al2, ar2);
  k_edge2<<<(N_NODES + 3) / 4, 256, 0, stream>>>(h2p, al2, ar2, rowptr, csr, b2, out);
}

// Round 4
// 315.937 us; speedup vs baseline: 2.4081x; 1.0868x over previous
//
#include <hip/hip_runtime.h>
#include <math.h>

#define N_NODES 100000
#define N_EDGES 1600000
#define E2 (N_EDGES + N_NODES)
#define NEG_SLOPE 0.2f

#define NPB 256                      // nodes per bucket
#define NB  ((N_NODES + NPB - 1) / NPB)   // 391 buckets
#define CAP 4800                     // per-bucket edge capacity
#define BCH 8192                     // edges per block in k_bucket

typedef unsigned int uint;
typedef unsigned short ushort;
typedef __attribute__((ext_vector_type(8))) short bf16x8;
typedef __attribute__((ext_vector_type(4))) float f32x4;

union U8 { uint4 q; bf16x8 v; uint u[4]; };

// ---------------- bf16 helpers ----------------

__device__ inline ushort f2bf(float x) {
  uint u = __float_as_uint(x);
  uint r = (u + 0x7FFFu + ((u >> 16) & 1u)) >> 16;   // RNE
  return (ushort)r;
}

__device__ inline uint pack2(float a, float b) {
  return (uint)f2bf(a) | ((uint)f2bf(b) << 16);
}

__device__ inline float bfval(ushort u) { return __uint_as_float((uint)u << 16); }

// unpack 8 bf16 (one uint4) -> 8 floats
__device__ inline void unpack8(uint4 q, float* f) {
  uint u[4] = {q.x, q.y, q.z, q.w};
#pragma unroll
  for (int k = 0; k < 4; ++k) {
    f[2 * k]     = __uint_as_float(u[k] << 16);
    f[2 * k + 1] = __uint_as_float(u[k] & 0xFFFF0000u);
  }
}

// ---------------- prep: W transposes (bf16) + bucket cursor init ----------------

__global__ __launch_bounds__(256) void k_prepW(const float* __restrict__ W1,
                                               const float* __restrict__ W2,
                                               ushort* __restrict__ WT1,
                                               ushort* __restrict__ WT2,
                                               int* __restrict__ bcursor) {
  int b = blockIdx.x, t = threadIdx.x;
  if (b == 0) {
    for (int i = t; i < 128 * 128; i += 256) {
      int k = i >> 7, n = i & 127;
      WT1[n * 128 + k] = f2bf(W1[i]);          // WT1[n][k]
    }
  } else if (b == 1) {
    for (int i = t; i < 48 * 128; i += 256) {
      int n = i >> 7, k = i & 127;
      WT2[i] = (n < 40) ? f2bf(W2[k * 40 + n]) : (ushort)0;   // WT2[n][k], zero-pad n>=40
    }
  } else {
    for (int i = t; i < NB; i += 256) bcursor[i] = i * CAP;
  }
}

// ---------------- bucketed CSR construction ----------------

__global__ __launch_bounds__(256) void k_bucket(const int* __restrict__ ei,
                                                int* __restrict__ bcursor,
                                                uint* __restrict__ pbuf) {
  __shared__ int cnt[NB];
  __shared__ int base[NB];
  const int tid = threadIdx.x;
  const int ebase = blockIdx.x * BCH;
  for (int t = tid; t < NB; t += 256) cnt[t] = 0;
  __syncthreads();
#pragma unroll 4
  for (int k = 0; k < BCH / 256; ++k) {
    int e = ebase + tid + k * 256;
    if (e < E2) {
      int d = (e < N_EDGES) ? ei[N_EDGES + e] : (e - N_EDGES);
      atomicAdd(&cnt[d >> 8], 1);
    }
  }
  __syncthreads();
  for (int t = tid; t < NB; t += 256) {
    int c = cnt[t];
    base[t] = c ? atomicAdd(&bcursor[t], c) : 0;
    cnt[t] = 0;
  }
  __syncthreads();
#pragma unroll 4
  for (int k = 0; k < BCH / 256; ++k) {
    int e = ebase + tid + k * 256;
    if (e < E2) {
      int s, d;
      if (e < N_EDGES) { s = ei[e]; d = ei[N_EDGES + e]; }
      else { s = e - N_EDGES; d = s; }
      int b = d >> 8;
      int pos = base[b] + atomicAdd(&cnt[b], 1);
      pbuf[pos] = ((uint)s << 8) | (uint)(d & 255);
    }
  }
}

__global__ __launch_bounds__(512) void k_scanB(const int* __restrict__ bcursor,
                                               int* __restrict__ bbase,
                                               int* __restrict__ rowptr) {
  __shared__ int sm[512];
  int t = threadIdx.x;
  int v = (t < NB) ? (bcursor[t] - t * CAP) : 0;
  sm[t] = v;
  __syncthreads();
  for (int off = 1; off < 512; off <<= 1) {
    int u = (t >= off) ? sm[t - off] : 0;
    __syncthreads();
    sm[t] += u;
    __syncthreads();
  }
  if (t < NB) bbase[t] = sm[t] - v;   // exclusive
  if (t == 0) rowptr[N_NODES] = E2;
}

__global__ __launch_bounds__(256) void k_csr(const uint* __restrict__ pbuf,
                                             const int* __restrict__ bcursor,
                                             const int* __restrict__ bbase,
                                             int* __restrict__ rowptr,
                                             int* __restrict__ csr) {
  __shared__ int hist[NPB];
  __shared__ int excl[NPB];
  __shared__ int cur[NPB];
  __shared__ int lcsr[CAP];
  const int b = blockIdx.x;
  const int tid = threadIdx.x;
  int count = bcursor[b] - b * CAP;
  if (count > CAP) count = CAP;
  const int gbase = bbase[b];
  const uint* seg = pbuf + b * CAP;
  hist[tid] = 0;
  __syncthreads();
  for (int k = tid; k < count; k += 256) atomicAdd(&hist[seg[k] & 255u], 1);
  __syncthreads();
  int own = hist[tid];
  excl[tid] = own;
  __syncthreads();
  for (int off = 1; off < 256; off <<= 1) {
    int u = (tid >= off) ? excl[tid - off] : 0;
    __syncthreads();
    excl[tid] += u;
    __syncthreads();
  }
  int ex = excl[tid] - own;
  cur[tid] = ex;
  int node = b * NPB + tid;
  if (node < N_NODES) rowptr[node] = gbase + ex;
  __syncthreads();
  for (int k = tid; k < count; k += 256) {
    uint pk = seg[k];
    int nd = pk & 255u;
    int pos = atomicAdd(&cur[nd], 1);
    lcsr[pos] = (int)(pk >> 8);
  }
  __syncthreads();
  for (int k = tid; k < count; k += 256) csr[gbase + k] = lcsr[k];
}

// ---------------- GEMM 1 (MFMA): h1 = bf16(x) @ bf16(W1)  [N,128]x[128,128] ----------------

__global__ __launch_bounds__(256) void k_gemm1m(const float* __restrict__ x,
                                                const ushort* __restrict__ WT1,
                                                ushort* __restrict__ h1b) {
  __shared__ ushort stg[4][16][128];
  const int tid = threadIdx.x;
  const int w = tid >> 6, l = tid & 63;
  const int r16 = l & 15, kq = l >> 4;
  const int rowbase = blockIdx.x * 64 + w * 16;
  int arow = rowbase + r16;
  if (arow > N_NODES - 1) arow = N_NODES - 1;
  // A-frags: row arow, k = t*32 + kq*8 + (0..7), converted fp32->bf16
  bf16x8 af[4];
  const float* xr = x + (size_t)arow * 128 + kq * 8;
#pragma unroll
  for (int t = 0; t < 4; ++t) {
    float4 a0 = *(const float4*)(xr + t * 32);
    float4 a1 = *(const float4*)(xr + t * 32 + 4);
    U8 u;
    u.u[0] = pack2(a0.x, a0.y); u.u[1] = pack2(a0.z, a0.w);
    u.u[2] = pack2(a1.x, a1.y); u.u[3] = pack2(a1.z, a1.w);
    af[t] = u.v;
  }
  f32x4 acc[8];
#pragma unroll
  for (int n = 0; n < 8; ++n) acc[n] = (f32x4){0.f, 0.f, 0.f, 0.f};
  const uint4* WT4 = (const uint4*)WT1;   // row = 16 uint4 (128 bf16)
#pragma unroll
  for (int t = 0; t < 4; ++t) {
#pragma unroll
    for (int n = 0; n < 8; ++n) {
      U8 b;
      b.q = WT4[(size_t)(n * 16 + r16) * 16 + t * 4 + kq];
      acc[n] = __builtin_amdgcn_mfma_f32_16x16x32_bf16(af[t], b.v, acc[n], 0, 0, 0);
    }
  }
  // D: row = kq*4 + r, col = n*16 + r16  -> stage to LDS, then coalesced bf16 rows out
#pragma unroll
  for (int n = 0; n < 8; ++n) {
#pragma unroll
    for (int r = 0; r < 4; ++r) stg[w][kq * 4 + r][n * 16 + r16] = f2bf(acc[n][r]);
  }
  __syncthreads();
  uint4* H1 = (uint4*)h1b;
  const uint4* S = (const uint4*)stg[w];
#pragma unroll
  for (int q = 0; q < 4; ++q) {
    int idx = l + q * 64;
    int row = idx >> 4, c4 = idx & 15;
    int grow = rowbase + row;
    if (grow < N_NODES) H1[(size_t)grow * 16 + c4] = S[idx];
  }
}

// ---------------- per-node attention scalars, layer 1 ----------------

__global__ __launch_bounds__(256) void k_alr1(const ushort* __restrict__ h1b,
                                              const float* __restrict__ attl,
                                              const float* __restrict__ attr,
                                              ushort* __restrict__ al_bf,
                                              float* __restrict__ ar) {
  int idx = blockIdx.x * 256 + threadIdx.x;
  if (idx >= N_NODES * 8) return;
  int n = idx >> 3, h = idx & 7;
  const uint4* H = (const uint4*)h1b;
  uint4 qa = H[(size_t)n * 16 + h * 2];
  uint4 qb = H[(size_t)n * 16 + h * 2 + 1];
  float f[16];
  unpack8(qa, f); unpack8(qb, f + 8);
  float sl = 0.f, sr = 0.f;
#pragma unroll
  for (int c = 0; c < 16; ++c) {
    sl += f[c] * attl[h * 16 + c];
    sr += f[c] * attr[h * 16 + c];
  }
  al_bf[idx] = f2bf(sl);
  ar[idx] = sr;
}

// ---------------- edge pass, layer 1: 4 groups x 16 lanes x 8ch, 2-edge unroll ----------------

__global__ __launch_bounds__(256) void k_edge1(const ushort* __restrict__ h1b,
                                               const ushort* __restrict__ al_bf,
                                               const float* __restrict__ ar,
                                               const int* __restrict__ rowptr,
                                               const int* __restrict__ csr,
                                               const float* __restrict__ b1,
                                               ushort* __restrict__ y1b) {
  int wid = (blockIdx.x * 256 + threadIdx.x) >> 6;
  int lane = threadIdx.x & 63;
  if (wid >= N_NODES) return;
  const int i = wid;
  const int l = lane & 15;   // channel slot: ch l*8 .. l*8+7
  const int g = lane >> 4;   // edge group 0..3
  const int h = l >> 1;      // head
  int start = rowptr[i], end = rowptr[i + 1];
  const uint4* H = (const uint4*)h1b;   // row = 16 uint4
  float hi[8];
  unpack8(H[(size_t)i * 16 + l], hi);
  float ar_i = ar[i * 8 + h];
  float s = 0.f;
  float acc[8] = {};
  for (int e = start + g; e < end; e += 8) {
    int e1 = e + 4;
    bool v1 = e1 < end;
    int j0 = csr[e];
    int j1 = v1 ? csr[e1] : j0;
    uint4 q0 = H[(size_t)j0 * 16 + l];
    uint4 q1 = H[(size_t)j1 * 16 + l];
    float al0 = bfval(al_bf[j0 * 8 + h]);
    float al1 = bfval(al_bf[j1 * 8 + h]);
    float hj0[8], hj1[8];
    unpack8(q0, hj0); unpack8(q1, hj1);
    float p0 = 0.f, p1 = 0.f;
#pragma unroll
    for (int c = 0; c < 8; ++c) { p0 += hi[c] * hj0[c]; p1 += hi[c] * hj1[c]; }
    p0 += __shfl_xor(p0, 1);
    p1 += __shfl_xor(p1, 1);
    float a0 = (al0 + ar_i) * (1.f / (1.f + __expf(-p0)));
    float a1 = (al1 + ar_i) * (1.f / (1.f + __expf(-p1)));
    a0 = a0 > 0.f ? a0 : NEG_SLOPE * a0;
    a1 = a1 > 0.f ? a1 : NEG_SLOPE * a1;
    float ex0 = __expf(a0);
    float ex1 = v1 ? __expf(a1) : 0.f;
    s += ex0 + ex1;
#pragma unroll
    for (int c = 0; c < 8; ++c) acc[c] += ex0 * hj0[c] + ex1 * hj1[c];
  }
#pragma unroll
  for (int mask = 16; mask <= 32; mask <<= 1) {
    s += __shfl_xor(s, mask);
#pragma unroll
    for (int c = 0; c < 8; ++c) acc[c] += __shfl_xor(acc[c], mask);
  }
  if (g == 0) {
    float inv = 1.f / s;
    float o[8];
#pragma unroll
    for (int c = 0; c < 8; ++c) {
      float v = acc[c] * inv + b1[l * 8 + c];
      o[c] = v > 0.f ? v : __expf(v) - 1.f;     // ELU
    }
    uint4 pk;
    pk.x = pack2(o[0], o[1]); pk.y = pack2(o[2], o[3]);
    pk.z = pack2(o[4], o[5]); pk.w = pack2(o[6], o[7]);
    ((uint4*)y1b)[(size_t)i * 16 + l] = pk;
  }
}

// ---------------- GEMM 2 (MFMA): h2 = y1b @ bf16(W2)  [N,128]x[128,48pad] -> [N,64] bf16 ----------------

__global__ __launch_bounds__(256) void k_gemm2m(const ushort* __restrict__ y1b,
                                                const ushort* __restrict__ WT2,
                                                ushort* __restrict__ h2p) {
  __shared__ ushort stg[4][16][48];
  const int tid = threadIdx.x;
  const int w = tid >> 6, l = tid & 63;
  const int r16 = l & 15, kq = l >> 4;
  const int rowbase = blockIdx.x * 64 + w * 16;
  int arow = rowbase + r16;
  if (arow > N_NODES - 1) arow = N_NODES - 1;
  const uint4* Y4 = (const uint4*)y1b;   // row = 16 uint4
  bf16x8 af[4];
#pragma unroll
  for (int t = 0; t < 4; ++t) {
    U8 u;
    u.q = Y4[(size_t)arow * 16 + t * 4 + kq];
    af[t] = u.v;
  }
  f32x4 acc[3];
#pragma unroll
  for (int n = 0; n < 3; ++n) acc[n] = (f32x4){0.f, 0.f, 0.f, 0.f};
  const uint4* WT4 = (const uint4*)WT2;   // 48 rows x 16 uint4
#pragma unroll
  for (int t = 0; t < 4; ++t) {
#pragma unroll
    for (int n = 0; n < 3; ++n) {
      U8 b;
      b.q = WT4[(size_t)(n * 16 + r16) * 16 + t * 4 + kq];
      acc[n] = __builtin_amdgcn_mfma_f32_16x16x32_bf16(af[t], b.v, acc[n], 0, 0, 0);
    }
  }
#pragma unroll
  for (int n = 0; n < 3; ++n) {
#pragma unroll
    for (int r = 0; r < 4; ++r) stg[w][kq * 4 + r][n * 16 + r16] = f2bf(acc[n][r]);
  }
  __syncthreads();
  uint4* H2 = (uint4*)h2p;               // row = 8 uint4 (64 bf16)
  const uint4* S = (const uint4*)stg[w]; // row = 6 uint4 (48 bf16)
  const uint4 z = make_uint4(0, 0, 0, 0);
#pragma unroll
  for (int q = 0; q < 2; ++q) {
    int idx = l + q * 64;                // 0..127
    int row = idx >> 3, c4 = idx & 7;
    int grow = rowbase + row;
    if (grow < N_NODES) H2[(size_t)grow * 8 + c4] = (c4 < 6) ? S[row * 6 + c4] : z;
  }
}

// ---------------- per-node attention scalars, layer 2 ----------------

__global__ __launch_bounds__(256) void k_alr2(const ushort* __restrict__ h2p,
                                              const float* __restrict__ attl,
                                              const float* __restrict__ attr,
                                              float* __restrict__ al,
                                              float* __restrict__ ar) {
  int n = blockIdx.x * 256 + threadIdx.x;
  if (n >= N_NODES) return;
  const uint4* H = (const uint4*)h2p;   // row = 8 uint4 (64 ch)
  float sl = 0.f, sr = 0.f;
#pragma unroll
  for (int q = 0; q < 5; ++q) {
    float f[8];
    unpack8(H[(size_t)n * 8 + q], f);
#pragma unroll
    for (int k = 0; k < 8; ++k) {
      sl += f[k] * attl[q * 8 + k];
      sr += f[k] * attr[q * 8 + k];
    }
  }
  al[n] = sl;
  ar[n] = sr;
}

// ---------------- edge pass, layer 2: 8 groups x 8 lanes x 8ch, 2-edge unroll + log_softmax ----------------

__global__ __launch_bounds__(256) void k_edge2(const ushort* __restrict__ h2p,
                                               const float* __restrict__ al,
                                               const float* __restrict__ ar,
                                               const int* __restrict__ rowptr,
                                               const int* __restrict__ csr,
                                               const float* __restrict__ b2,
                                               float* __restrict__ out) {
  int wid = (blockIdx.x * 256 + threadIdx.x) >> 6;
  int lane = threadIdx.x & 63;
  if (wid >= N_NODES) return;
  const int i = wid;
  const int l = lane & 7;    // channel slot (pads >= 40 are zero)
  const int g = lane >> 3;   // edge group 0..7
  int start = rowptr[i], end = rowptr[i + 1];
  const uint4* H = (const uint4*)h2p;   // row = 8 uint4
  float hi[8];
  unpack8(H[(size_t)i * 8 + l], hi);
  float ar_i = ar[i];
  float s = 0.f;
  float acc[8] = {};
  for (int e = start + g; e < end; e += 16) {
    int e1 = e + 8;
    bool v1 = e1 < end;
    int j0 = csr[e];
    int j1 = v1 ? csr[e1] : j0;
    uint4 q0 = H[(size_t)j0 * 8 + l];
    uint4 q1 = H[(size_t)j1 * 8 + l];
    float al0 = al[j0];
    float al1 = al[j1];
    float hj0[8], hj1[8];
    unpack8(q0, hj0); unpack8(q1, hj1);
    float p0 = 0.f, p1 = 0.f;
#pragma unroll
    for (int c = 0; c < 8; ++c) { p0 += hi[c] * hj0[c]; p1 += hi[c] * hj1[c]; }
    p0 += __shfl_xor(p0, 1); p1 += __shfl_xor(p1, 1);
    p0 += __shfl_xor(p0, 2); p1 += __shfl_xor(p1, 2);
    p0 += __shfl_xor(p0, 4); p1 += __shfl_xor(p1, 4);
    float a0 = (al0 + ar_i) * (1.f / (1.f + __expf(-p0)));
    float a1 = (al1 + ar_i) * (1.f / (1.f + __expf(-p1)));
    a0 = a0 > 0.f ? a0 : NEG_SLOPE * a0;
    a1 = a1 > 0.f ? a1 : NEG_SLOPE * a1;
    float ex0 = __expf(a0);
    float ex1 = v1 ? __expf(a1) : 0.f;
    s += ex0 + ex1;
#pragma unroll
    for (int c = 0; c < 8; ++c) acc[c] += ex0 * hj0[c] + ex1 * hj1[c];
  }
#pragma unroll
  for (int mask = 8; mask <= 32; mask <<= 1) {
    s += __shfl_xor(s, mask);
#pragma unroll
    for (int c = 0; c < 8; ++c) acc[c] += __shfl_xor(acc[c], mask);
  }
  float inv = 1.f / s;
  bool act = l < 5;
  float o[8];
  float mx = -1e30f;
#pragma unroll
  for (int c = 0; c < 8; ++c) {
    float b = act ? b2[l * 8 + c] : 0.f;
    o[c] = acc[c] * inv + b;
    if (act) mx = fmaxf(mx, o[c]);
  }
  mx = fmaxf(mx, __shfl_xor(mx, 1));
  mx = fmaxf(mx, __shfl_xor(mx, 2));
  mx = fmaxf(mx, __shfl_xor(mx, 4));
  float se = 0.f;
  if (act) {
#pragma unroll
    for (int c = 0; c < 8; ++c) se += __expf(o[c] - mx);
  }
  se += __shfl_xor(se, 1);
  se += __shfl_xor(se, 2);
  se += __shfl_xor(se, 4);
  if (g == 0 && act) {
    float lse = mx + __logf(se);
    float4 r0 = make_float4(o[0] - lse, o[1] - lse, o[2] - lse, o[3] - lse);
    float4 r1 = make_float4(o[4] - lse, o[5] - lse, o[6] - lse, o[7] - lse);
    float4* O = (float4*)(out + (size_t)i * 40 + l * 8);
    O[0] = r0;
    O[1] = r1;
  }
}

// ---------------- launcher ----------------

extern "C" void kernel_launch(void* const* d_in, const int* in_sizes, int n_in,
                              void* d_out, int out_size, void* d_ws, size_t ws_size,
                              hipStream_t stream) {
  const float* x     = (const float*)d_in[0];
  const int*   ei    = (const int*)d_in[1];
  const float* W1    = (const float*)d_in[2];
  const float* attl1 = (const float*)d_in[3];
  const float* attr1 = (const float*)d_in[4];
  const float* b1    = (const float*)d_in[5];
  const float* W2    = (const float*)d_in[6];
  const float* attl2 = (const float*)d_in[7];
  const float* attr2 = (const float*)d_in[8];
  const float* b2    = (const float*)d_in[9];
  float* out = (float*)d_out;

  char* wsp = (char*)d_ws;
  size_t off = 0;
  auto alloc = [&](size_t bytes) {
    char* p = wsp + off;
    off = (off + bytes + 255) & ~(size_t)255;
    return p;
  };
  ushort* h1b   = (ushort*)alloc((size_t)N_NODES * 128 * 2);  // bf16 h1
  ushort* y1b   = (ushort*)alloc((size_t)N_NODES * 128 * 2);  // bf16 y1
  ushort* al1b  = (ushort*)alloc((size_t)N_NODES * 8 * 2);    // bf16 al1
  float* ar1    = (float*)alloc((size_t)N_NODES * 8 * 4);
  int* rowptr   = (int*)alloc((size_t)(N_NODES + 1) * 4);
  int* bcursor  = (int*)alloc((size_t)NB * 4);
  int* bbase    = (int*)alloc((size_t)NB * 4);
  int* csr      = (int*)alloc((size_t)E2 * 4);
  ushort* WT1   = (ushort*)alloc(128 * 128 * 2);
  ushort* WT2   = (ushort*)alloc(48 * 128 * 2);
  uint* pbuf  = (uint*)y1b;   // overlay: pbuf (7.5MB) dead before edge1 writes y1b
  ushort* h2p = h1b;          // reuse: h1b dead after edge1
  float* al2  = (float*)ar1;  // reuse: ar1/al1b dead after edge1
  float* ar2  = al2 + N_NODES;

  // prep + CSR build
  k_prepW<<<3, 256, 0, stream>>>(W1, W2, WT1, WT2, bcursor);
  k_bucket<<<(E2 + BCH - 1) / BCH, 256, 0, stream>>>(ei, bcursor, pbuf);
  k_scanB<<<1, 512, 0, stream>>>(bcursor, bbase, rowptr);
  k_csr<<<NB, 256, 0, stream>>>(pbuf, bcursor, bbase, rowptr, csr);

  // layer 1
  k_gemm1m<<<(N_NODES + 63) / 64, 256, 0, stream>>>(x, WT1, h1b);
  k_alr1<<<(N_NODES * 8 + 255) / 256, 256, 0, stream>>>(h1b, attl1, attr1, al1b, ar1);
  k_edge1<<<(N_NODES + 3) / 4, 256, 0, stream>>>(h1b, al1b, ar1, rowptr, csr, b1, y1b);

  // layer 2
  k_gemm2m<<<(N_NODES + 63) / 64, 256, 0, stream>>>(y1b, WT2, h2p);
  k_alr2<<<(N_NODES + 255) / 256, 256, 0, stream>>>(h2p, attl2, attr2, al2, ar2);
  k_edge2<<<(N_NODES + 3) / 4, 256, 0, stream>>>(h2p, al2, ar2, rowptr, csr, b2, out);
}

// Round 6
// 275.829 us; speedup vs baseline: 2.7583x; 1.1454x over previous
//
#include <hip/hip_runtime.h>
#include <math.h>

#define N_NODES 100000
#define N_EDGES 1600000
#define E2 (N_EDGES + N_NODES)
#define NEG_SLOPE 0.2f

#define NPB 256                      // nodes per bucket
#define NB  ((N_NODES + NPB - 1) / NPB)   // 391 buckets
#define CAP 4800                     // per-bucket edge capacity
#define BCH 8192                     // edges per block in k_bucket

typedef unsigned int uint;
typedef unsigned short ushort;
typedef __attribute__((ext_vector_type(2))) _Float16 h2_t;
typedef __attribute__((ext_vector_type(8))) _Float16 f16x8;
typedef __attribute__((ext_vector_type(4))) float f32x4;

union U8 { uint4 q; f16x8 v; h2_t h2[4]; _Float16 h[8]; uint u[4]; };

// ---------------- fp16 helpers ----------------

__device__ inline ushort f2h(float x) {
  _Float16 h = (_Float16)x;
  return *(ushort*)&h;
}

__device__ inline float h2f(ushort u) {
  _Float16 h = *(_Float16*)&u;
  return (float)h;
}

__device__ inline h2_t pk2h(float a, float b) {
  auto r = __builtin_amdgcn_cvt_pkrtz(a, b);   // __fp16 vec2 -> bit-cast
  return *(h2_t*)&r;
}

__device__ inline float fdot2(h2_t a, h2_t b, float c) {
#if __has_builtin(__builtin_amdgcn_fdot2)
  return __builtin_amdgcn_fdot2(*(__fp16 __attribute__((ext_vector_type(2)))*)&a,
                                *(__fp16 __attribute__((ext_vector_type(2)))*)&b,
                                c, false);
#else
  return c + (float)a.x * (float)b.x + (float)a.y * (float)b.y;
#endif
}

// ---------------- prep: W transposes (fp16) + bucket cursor init ----------------

__global__ __launch_bounds__(256) void k_prepW(const float* __restrict__ W1,
                                               const float* __restrict__ W2,
                                               ushort* __restrict__ WT1,
                                               ushort* __restrict__ WT2,
                                               int* __restrict__ bcursor) {
  int b = blockIdx.x, t = threadIdx.x;
  if (b == 0) {
    for (int i = t; i < 128 * 128; i += 256) {
      int k = i >> 7, n = i & 127;
      WT1[n * 128 + k] = f2h(W1[i]);           // WT1[n][k]
    }
  } else if (b == 1) {
    for (int i = t; i < 48 * 128; i += 256) {
      int n = i >> 7, k = i & 127;
      WT2[i] = (n < 40) ? f2h(W2[k * 40 + n]) : (ushort)0;   // WT2[n][k], zero-pad n>=40
    }
  } else {
    for (int i = t; i < NB; i += 256) bcursor[i] = i * CAP;
  }
}

// ---------------- bucketed CSR construction ----------------

__global__ __launch_bounds__(256) void k_bucket(const int* __restrict__ ei,
                                                int* __restrict__ bcursor,
                                                uint* __restrict__ pbuf) {
  __shared__ int cnt[NB];
  __shared__ int base[NB];
  const int tid = threadIdx.x;
  const int ebase = blockIdx.x * BCH;
  for (int t = tid; t < NB; t += 256) cnt[t] = 0;
  __syncthreads();
#pragma unroll 4
  for (int k = 0; k < BCH / 256; ++k) {
    int e = ebase + tid + k * 256;
    if (e < E2) {
      int d = (e < N_EDGES) ? ei[N_EDGES + e] : (e - N_EDGES);
      atomicAdd(&cnt[d >> 8], 1);
    }
  }
  __syncthreads();
  for (int t = tid; t < NB; t += 256) {
    int c = cnt[t];
    base[t] = c ? atomicAdd(&bcursor[t], c) : 0;
    cnt[t] = 0;
  }
  __syncthreads();
#pragma unroll 4
  for (int k = 0; k < BCH / 256; ++k) {
    int e = ebase + tid + k * 256;
    if (e < E2) {
      int s, d;
      if (e < N_EDGES) { s = ei[e]; d = ei[N_EDGES + e]; }
      else { s = e - N_EDGES; d = s; }
      int b = d >> 8;
      int pos = base[b] + atomicAdd(&cnt[b], 1);
      pbuf[pos] = ((uint)s << 8) | (uint)(d & 255);
    }
  }
}

__global__ __launch_bounds__(512) void k_scanB(const int* __restrict__ bcursor,
                                               int* __restrict__ bbase,
                                               int* __restrict__ rowptr) {
  __shared__ int sm[512];
  int t = threadIdx.x;
  int v = (t < NB) ? (bcursor[t] - t * CAP) : 0;
  sm[t] = v;
  __syncthreads();
  for (int off = 1; off < 512; off <<= 1) {
    int u = (t >= off) ? sm[t - off] : 0;
    __syncthreads();
    sm[t] += u;
    __syncthreads();
  }
  if (t < NB) bbase[t] = sm[t] - v;   // exclusive
  if (t == 0) rowptr[N_NODES] = E2;
}

__global__ __launch_bounds__(256) void k_csr(const uint* __restrict__ pbuf,
                                             const int* __restrict__ bcursor,
                                             const int* __restrict__ bbase,
                                             int* __restrict__ rowptr,
                                             int* __restrict__ csr) {
  __shared__ int hist[NPB];
  __shared__ int excl[NPB];
  __shared__ int cur[NPB];
  __shared__ int lcsr[CAP];
  const int b = blockIdx.x;
  const int tid = threadIdx.x;
  int count = bcursor[b] - b * CAP;
  if (count > CAP) count = CAP;
  const int gbase = bbase[b];
  const uint* seg = pbuf + b * CAP;
  hist[tid] = 0;
  __syncthreads();
  for (int k = tid; k < count; k += 256) atomicAdd(&hist[seg[k] & 255u], 1);
  __syncthreads();
  int own = hist[tid];
  excl[tid] = own;
  __syncthreads();
  for (int off = 1; off < 256; off <<= 1) {
    int u = (tid >= off) ? excl[tid - off] : 0;
    __syncthreads();
    excl[tid] += u;
    __syncthreads();
  }
  int ex = excl[tid] - own;
  cur[tid] = ex;
  int node = b * NPB + tid;
  if (node < N_NODES) rowptr[node] = gbase + ex;
  __syncthreads();
  for (int k = tid; k < count; k += 256) {
    uint pk = seg[k];
    int nd = pk & 255u;
    int pos = atomicAdd(&cur[nd], 1);
    lcsr[pos] = (int)(pk >> 8);
  }
  __syncthreads();
  for (int k = tid; k < count; k += 256) csr[gbase + k] = lcsr[k];
}

// ---------------- GEMM 1 (MFMA f16) + fused alr1 ----------------

__global__ __launch_bounds__(256) void k_gemm1m(const float* __restrict__ x,
                                                const ushort* __restrict__ WT1,
                                                const float* __restrict__ attl,
                                                const float* __restrict__ attr,
                                                ushort* __restrict__ h1h,
                                                ushort* __restrict__ al1h,
                                                float* __restrict__ ar1) {
  __shared__ ushort stg[4][16][136];   // pad 128->136 (17 uint4/row)
  __shared__ h2_t attl_sm[64], attr_sm[64];
  const int tid = threadIdx.x;
  const int w = tid >> 6, l = tid & 63;
  const int r16 = l & 15, kq = l >> 4;
  const int rowbase = blockIdx.x * 64 + w * 16;
  if (tid < 64) attl_sm[tid] = pk2h(attl[2 * tid], attl[2 * tid + 1]);
  else if (tid < 128) { int t = tid - 64; attr_sm[t] = pk2h(attr[2 * t], attr[2 * t + 1]); }
  int arow = rowbase + r16;
  if (arow > N_NODES - 1) arow = N_NODES - 1;
  // A-frags: row arow, k = t*32 + kq*8 + (0..7), fp32 -> fp16
  f16x8 af[4];
  const float* xr = x + (size_t)arow * 128 + kq * 8;
#pragma unroll
  for (int t = 0; t < 4; ++t) {
    float4 a0 = *(const float4*)(xr + t * 32);
    float4 a1 = *(const float4*)(xr + t * 32 + 4);
    U8 u;
    u.h2[0] = pk2h(a0.x, a0.y); u.h2[1] = pk2h(a0.z, a0.w);
    u.h2[2] = pk2h(a1.x, a1.y); u.h2[3] = pk2h(a1.z, a1.w);
    af[t] = u.v;
  }
  f32x4 acc[8];
#pragma unroll
  for (int n = 0; n < 8; ++n) acc[n] = (f32x4){0.f, 0.f, 0.f, 0.f};
  const uint4* WT4 = (const uint4*)WT1;   // row = 16 uint4 (128 fp16)
#pragma unroll
  for (int t = 0; t < 4; ++t) {
#pragma unroll
    for (int n = 0; n < 8; ++n) {
      U8 b;
      b.q = WT4[(size_t)(n * 16 + r16) * 16 + t * 4 + kq];
      acc[n] = __builtin_amdgcn_mfma_f32_16x16x32_f16(af[t], b.v, acc[n], 0, 0, 0);
    }
  }
  // D: row = kq*4 + r, col = n*16 + r16
#pragma unroll
  for (int n = 0; n < 8; ++n) {
#pragma unroll
    for (int r = 0; r < 4; ++r) stg[w][kq * 4 + r][n * 16 + r16] = f2h(acc[n][r]);
  }
  __syncthreads();
  // coalesced row write-out
  uint4* H1 = (uint4*)h1h;
  const uint4* S = (const uint4*)stg[w];   // row stride 17 uint4
#pragma unroll
  for (int q = 0; q < 4; ++q) {
    int idx = l + q * 64;
    int row = idx >> 4, c4 = idx & 15;
    int grow = rowbase + row;
    if (grow < N_NODES) H1[(size_t)grow * 16 + c4] = S[row * 17 + c4];
  }
  // fused alr1: 128 (row,head) pairs per wave, 2 per lane
#pragma unroll
  for (int p = 0; p < 2; ++p) {
    int pidx = l + p * 64;
    int row = pidx >> 3, h = pidx & 7;
    int grow = rowbase + row;
    U8 a0, a1;
    a0.q = S[row * 17 + h * 2];
    a1.q = S[row * 17 + h * 2 + 1];
    float sl = 0.f, sr = 0.f;
#pragma unroll
    for (int k = 0; k < 4; ++k) {
      sl = fdot2(a0.h2[k], attl_sm[h * 8 + k], sl);
      sr = fdot2(a0.h2[k], attr_sm[h * 8 + k], sr);
      sl = fdot2(a1.h2[k], attl_sm[h * 8 + 4 + k], sl);
      sr = fdot2(a1.h2[k], attr_sm[h * 8 + 4 + k], sr);
    }
    if (grow < N_NODES) {
      al1h[(size_t)grow * 8 + h] = f2h(sl);
      ar1[(size_t)grow * 8 + h] = sr;
    }
  }
}

// ---------------- edge pass, layer 1: 4 groups x 16 lanes x 8ch, 2-edge unroll ----------------

__global__ __launch_bounds__(256) void k_edge1(const ushort* __restrict__ h1h,
                                               const ushort* __restrict__ al1h,
                                               const float* __restrict__ ar1,
                                               const int* __restrict__ rowptr,
                                               const int* __restrict__ csr,
                                               const float* __restrict__ b1,
                                               ushort* __restrict__ y1h) {
  int wid = (blockIdx.x * 256 + threadIdx.x) >> 6;
  int lane = threadIdx.x & 63;
  if (wid >= N_NODES) return;
  const int i = wid;
  const int l = lane & 15;   // channel slot: ch l*8 .. l*8+7
  const int g = lane >> 4;   // edge group 0..3
  const int h = l >> 1;      // head
  int start = rowptr[i], end = rowptr[i + 1];
  const uint4* H = (const uint4*)h1h;   // row = 16 uint4
  U8 uhi;
  uhi.q = H[(size_t)i * 16 + l];
  float ar_i = ar1[i * 8 + h];
  float s = 0.f;
  float acc[8] = {};
  for (int e = start + g; e < end; e += 8) {
    int e1 = e + 4;
    bool v1 = e1 < end;
    int j0 = csr[e];
    int j1 = v1 ? csr[e1] : j0;
    U8 u0, u1;
    u0.q = H[(size_t)j0 * 16 + l];
    u1.q = H[(size_t)j1 * 16 + l];
    float al0 = h2f(al1h[j0 * 8 + h]);
    float al1 = h2f(al1h[j1 * 8 + h]);
    float p0 = 0.f, p1 = 0.f;
#pragma unroll
    for (int k = 0; k < 4; ++k) {
      p0 = fdot2(uhi.h2[k], u0.h2[k], p0);
      p1 = fdot2(uhi.h2[k], u1.h2[k], p1);
    }
    p0 += __shfl_xor(p0, 1);
    p1 += __shfl_xor(p1, 1);
    float a0 = (al0 + ar_i) * (1.f / (1.f + __expf(-p0)));
    float a1 = (al1 + ar_i) * (1.f / (1.f + __expf(-p1)));
    a0 = fmaxf(a0, NEG_SLOPE * a0);
    a1 = fmaxf(a1, NEG_SLOPE * a1);
    float ex0 = __expf(a0);
    float ex1 = v1 ? __expf(a1) : 0.f;
    s += ex0 + ex1;
#pragma unroll
    for (int c = 0; c < 8; ++c) {
      acc[c] = fmaf(ex0, (float)u0.h[c], acc[c]);
      acc[c] = fmaf(ex1, (float)u1.h[c], acc[c]);
    }
  }
#pragma unroll
  for (int mask = 16; mask <= 32; mask <<= 1) {
    s += __shfl_xor(s, mask);
#pragma unroll
    for (int c = 0; c < 8; ++c) acc[c] += __shfl_xor(acc[c], mask);
  }
  if (g == 0) {
    float inv = 1.f / s;
    float o[8];
#pragma unroll
    for (int c = 0; c < 8; ++c) {
      float v = acc[c] * inv + b1[l * 8 + c];
      o[c] = v > 0.f ? v : __expf(v) - 1.f;     // ELU
    }
    U8 pk;
#pragma unroll
    for (int c = 0; c < 4; ++c) pk.h2[c] = pk2h(o[2 * c], o[2 * c + 1]);
    ((uint4*)y1h)[(size_t)i * 16 + l] = pk.q;
  }
}

// ---------------- GEMM 2 (MFMA f16) + fused alr2 ----------------

__global__ __launch_bounds__(256) void k_gemm2m(const ushort* __restrict__ y1h,
                                                const ushort* __restrict__ WT2,
                                                const float* __restrict__ attl,
                                                const float* __restrict__ attr,
                                                ushort* __restrict__ h2p,
                                                float* __restrict__ al2,
                                                float* __restrict__ ar2) {
  __shared__ ushort stg[4][16][56];    // pad 48->56 (7 uint4/row)
  __shared__ h2_t attl_sm[20], attr_sm[20];
  const int tid = threadIdx.x;
  const int w = tid >> 6, l = tid & 63;
  const int r16 = l & 15, kq = l >> 4;
  const int rowbase = blockIdx.x * 64 + w * 16;
  if (tid < 20) attl_sm[tid] = pk2h(attl[2 * tid], attl[2 * tid + 1]);
  else if (tid >= 32 && tid < 52) { int t = tid - 32; attr_sm[t] = pk2h(attr[2 * t], attr[2 * t + 1]); }
  int arow = rowbase + r16;
  if (arow > N_NODES - 1) arow = N_NODES - 1;
  const uint4* Y4 = (const uint4*)y1h;   // row = 16 uint4
  f16x8 af[4];
#pragma unroll
  for (int t = 0; t < 4; ++t) {
    U8 u;
    u.q = Y4[(size_t)arow * 16 + t * 4 + kq];
    af[t] = u.v;
  }
  f32x4 acc[3];
#pragma unroll
  for (int n = 0; n < 3; ++n) acc[n] = (f32x4){0.f, 0.f, 0.f, 0.f};
  const uint4* WT4 = (const uint4*)WT2;   // 48 rows x 16 uint4
#pragma unroll
  for (int t = 0; t < 4; ++t) {
#pragma unroll
    for (int n = 0; n < 3; ++n) {
      U8 b;
      b.q = WT4[(size_t)(n * 16 + r16) * 16 + t * 4 + kq];
      acc[n] = __builtin_amdgcn_mfma_f32_16x16x32_f16(af[t], b.v, acc[n], 0, 0, 0);
    }
  }
#pragma unroll
  for (int n = 0; n < 3; ++n) {
#pragma unroll
    for (int r = 0; r < 4; ++r) stg[w][kq * 4 + r][n * 16 + r16] = f2h(acc[n][r]);
  }
  __syncthreads();
  uint4* H2 = (uint4*)h2p;               // row = 8 uint4 (64 fp16)
  const uint4* S = (const uint4*)stg[w]; // row stride 7 uint4
  const uint4 z = make_uint4(0, 0, 0, 0);
#pragma unroll
  for (int q = 0; q < 2; ++q) {
    int idx = l + q * 64;                // 0..127
    int row = idx >> 3, c4 = idx & 7;
    int grow = rowbase + row;
    if (grow < N_NODES) H2[(size_t)grow * 8 + c4] = (c4 < 6) ? S[row * 7 + c4] : z;
  }
  // fused alr2: 16 rows x {al, ar} = 32 tasks on lanes 0..31
  if (l < 32) {
    int row = l & 15, sel = l >> 4;
    int grow = rowbase + row;
    const h2_t* att = sel ? attr_sm : attl_sm;
    float v = 0.f;
#pragma unroll
    for (int q = 0; q < 5; ++q) {
      U8 b;
      b.q = S[row * 7 + q];
#pragma unroll
      for (int k = 0; k < 4; ++k) v = fdot2(b.h2[k], att[q * 4 + k], v);
    }
    if (grow < N_NODES) {
      if (sel) ar2[grow] = v;
      else     al2[grow] = v;
    }
  }
}

// ---------------- edge pass, layer 2: 8 groups x 8 lanes x 8ch + log_softmax ----------------

__global__ __launch_bounds__(256) void k_edge2(const ushort* __restrict__ h2p,
                                               const float* __restrict__ al,
                                               const float* __restrict__ ar,
                                               const int* __restrict__ rowptr,
                                               const int* __restrict__ csr,
                                               const float* __restrict__ b2,
                                               float* __restrict__ out) {
  int wid = (blockIdx.x * 256 + threadIdx.x) >> 6;
  int lane = threadIdx.x & 63;
  if (wid >= N_NODES) return;
  const int i = wid;
  const int l = lane & 7;    // channel slot (pads >= 40 are zero)
  const int g = lane >> 3;   // edge group 0..7
  int start = rowptr[i], end = rowptr[i + 1];
  const uint4* H = (const uint4*)h2p;   // row = 8 uint4
  U8 uhi;
  uhi.q = H[(size_t)i * 8 + l];
  float ar_i = ar[i];
  float s = 0.f;
  float acc[8] = {};
  for (int e = start + g; e < end; e += 16) {
    int e1 = e + 8;
    bool v1 = e1 < end;
    int j0 = csr[e];
    int j1 = v1 ? csr[e1] : j0;
    U8 u0, u1;
    u0.q = H[(size_t)j0 * 8 + l];
    u1.q = H[(size_t)j1 * 8 + l];
    float al0 = al[j0];
    float al1 = al[j1];
    float p0 = 0.f, p1 = 0.f;
#pragma unroll
    for (int k = 0; k < 4; ++k) {
      p0 = fdot2(uhi.h2[k], u0.h2[k], p0);
      p1 = fdot2(uhi.h2[k], u1.h2[k], p1);
    }
    p0 += __shfl_xor(p0, 1); p1 += __shfl_xor(p1, 1);
    p0 += __shfl_xor(p0, 2); p1 += __shfl_xor(p1, 2);
    p0 += __shfl_xor(p0, 4); p1 += __shfl_xor(p1, 4);
    float a0 = (al0 + ar_i) * (1.f / (1.f + __expf(-p0)));
    float a1 = (al1 + ar_i) * (1.f / (1.f + __expf(-p1)));
    a0 = fmaxf(a0, NEG_SLOPE * a0);
    a1 = fmaxf(a1, NEG_SLOPE * a1);
    float ex0 = __expf(a0);
    float ex1 = v1 ? __expf(a1) : 0.f;
    s += ex0 + ex1;
#pragma unroll
    for (int c = 0; c < 8; ++c) {
      acc[c] = fmaf(ex0, (float)u0.h[c], acc[c]);
      acc[c] = fmaf(ex1, (float)u1.h[c], acc[c]);
    }
  }
#pragma unroll
  for (int mask = 8; mask <= 32; mask <<= 1) {
    s += __shfl_xor(s, mask);
#pragma unroll
    for (int c = 0; c < 8; ++c) acc[c] += __shfl_xor(acc[c], mask);
  }
  float inv = 1.f / s;
  bool act = l < 5;
  float o[8];
  float mx = -1e30f;
#pragma unroll
  for (int c = 0; c < 8; ++c) {
    float b = act ? b2[l * 8 + c] : 0.f;
    o[c] = acc[c] * inv + b;
    if (act) mx = fmaxf(mx, o[c]);
  }
  mx = fmaxf(mx, __shfl_xor(mx, 1));
  mx = fmaxf(mx, __shfl_xor(mx, 2));
  mx = fmaxf(mx, __shfl_xor(mx, 4));
  float se = 0.f;
  if (act) {
#pragma unroll
    for (int c = 0; c < 8; ++c) se += __expf(o[c] - mx);
  }
  se += __shfl_xor(se, 1);
  se += __shfl_xor(se, 2);
  se += __shfl_xor(se, 4);
  if (g == 0 && act) {
    float lse = mx + __logf(se);
    float4 r0 = make_float4(o[0] - lse, o[1] - lse, o[2] - lse, o[3] - lse);
    float4 r1 = make_float4(o[4] - lse, o[5] - lse, o[6] - lse, o[7] - lse);
    float4* O = (float4*)(out + (size_t)i * 40 + l * 8);
    O[0] = r0;
    O[1] = r1;
  }
}

// ---------------- launcher ----------------

extern "C" void kernel_launch(void* const* d_in, const int* in_sizes, int n_in,
                              void* d_out, int out_size, void* d_ws, size_t ws_size,
                              hipStream_t stream) {
  const float* x     = (const float*)d_in[0];
  const int*   ei    = (const int*)d_in[1];
  const float* W1    = (const float*)d_in[2];
  const float* attl1 = (const float*)d_in[3];
  const float* attr1 = (const float*)d_in[4];
  const float* b1    = (const float*)d_in[5];
  const float* W2    = (const float*)d_in[6];
  const float* attl2 = (const float*)d_in[7];
  const float* attr2 = (const float*)d_in[8];
  const float* b2    = (const float*)d_in[9];
  float* out = (float*)d_out;

  char* wsp = (char*)d_ws;
  size_t off = 0;
  auto alloc = [&](size_t bytes) {
    char* p = wsp + off;
    off = (off + bytes + 255) & ~(size_t)255;
    return p;
  };
  ushort* h1h   = (ushort*)alloc((size_t)N_NODES * 128 * 2);  // fp16 h1
  ushort* y1h   = (ushort*)alloc((size_t)N_NODES * 128 * 2);  // fp16 y1
  ushort* al1h  = (ushort*)alloc((size_t)N_NODES * 8 * 2);    // fp16 al1
  float* ar1    = (float*)alloc((size_t)N_NODES * 8 * 4);
  int* rowptr   = (int*)alloc((size_t)(N_NODES + 1) * 4);
  int* bcursor  = (int*)alloc((size_t)NB * 4);
  int* bbase    = (int*)alloc((size_t)NB * 4);
  int* csr      = (int*)alloc((size_t)E2 * 4);
  ushort* WT1   = (ushort*)alloc(128 * 128 * 2);
  ushort* WT2   = (ushort*)alloc(48 * 128 * 2);
  uint* pbuf  = (uint*)y1h;   // overlay: pbuf (7.5MB) dead before edge1 writes y1h
  ushort* h2p = h1h;          // reuse: h1h dead after edge1
  float* al2  = (float*)ar1;  // reuse: ar1/al1h dead after edge1
  float* ar2  = al2 + N_NODES;

  // prep + CSR build
  k_prepW<<<3, 256, 0, stream>>>(W1, W2, WT1, WT2, bcursor);
  k_bucket<<<(E2 + BCH - 1) / BCH, 256, 0, stream>>>(ei, bcursor, pbuf);
  k_scanB<<<1, 512, 0, stream>>>(bcursor, bbase, rowptr);
  k_csr<<<NB, 256, 0, stream>>>(pbuf, bcursor, bbase, rowptr, csr);

  // layer 1
  k_gemm1m<<<(N_NODES + 63) / 64, 256, 0, stream>>>(x, WT1, attl1, attr1, h1h, al1h, ar1);
  k_edge1<<<(N_NODES + 3) / 4, 256, 0, stream>>>(h1h, al1h, ar1, rowptr, csr, b1, y1h);

  // layer 2
  k_gemm2m<<<(N_NODES + 63) / 64, 256, 0, stream>>>(y1h, WT2, attl2, attr2, h2p, al2, ar2);
  k_edge2<<<(N_NODES + 3) / 4, 256, 0, stream>>>(h2p, al2, ar2, rowptr, csr, b2, out);
}

// Round 7
// 251.856 us; speedup vs baseline: 3.0208x; 1.0952x over previous
//
#include <hip/hip_runtime.h>
#include <math.h>

#define N_NODES 100000
#define N_EDGES 1600000
#define E2 (N_EDGES + N_NODES)
#define NEG_SLOPE 0.2f

#define NPB 256                      // nodes per bucket
#define NB  ((N_NODES + NPB - 1) / NPB)   // 391 buckets
#define CAP 4800                     // per-bucket edge capacity
#define BCH 8192                     // edges per block in k_bucket

typedef unsigned int uint;
typedef unsigned short ushort;
typedef __attribute__((ext_vector_type(2))) _Float16 h2_t;
typedef __attribute__((ext_vector_type(8))) _Float16 f16x8;
typedef __attribute__((ext_vector_type(4))) float f32x4;

union U8 { uint4 q; f16x8 v; h2_t h2[4]; _Float16 h[8]; uint u[4]; };

// ---------------- fp16 helpers ----------------

__device__ inline ushort f2h(float x) {
  _Float16 h = (_Float16)x;
  return *(ushort*)&h;
}

__device__ inline float h2f(ushort u) {
  _Float16 h = *(_Float16*)&u;
  return (float)h;
}

__device__ inline h2_t pk2h(float a, float b) {
  auto r = __builtin_amdgcn_cvt_pkrtz(a, b);   // __fp16 vec2 -> bit-cast
  return *(h2_t*)&r;
}

__device__ inline float fdot2(h2_t a, h2_t b, float c) {
#if __has_builtin(__builtin_amdgcn_fdot2)
  return __builtin_amdgcn_fdot2(*(__fp16 __attribute__((ext_vector_type(2)))*)&a,
                                *(__fp16 __attribute__((ext_vector_type(2)))*)&b,
                                c, false);
#else
  return c + (float)a.x * (float)b.x + (float)a.y * (float)b.y;
#endif
}

// ---------------- prep: W transposes (fp16) + bucket cursor init ----------------

__global__ __launch_bounds__(256) void k_prepW(const float* __restrict__ W1,
                                               const float* __restrict__ W2,
                                               ushort* __restrict__ WT1,
                                               ushort* __restrict__ WT2,
                                               int* __restrict__ bcursor) {
  int b = blockIdx.x, t = threadIdx.x;
  if (b == 0) {
    for (int i = t; i < 128 * 128; i += 256) {
      int k = i >> 7, n = i & 127;
      WT1[n * 128 + k] = f2h(W1[i]);           // WT1[n][k]
    }
  } else if (b == 1) {
    for (int i = t; i < 48 * 128; i += 256) {
      int n = i >> 7, k = i & 127;
      WT2[i] = (n < 40) ? f2h(W2[k * 40 + n]) : (ushort)0;   // WT2[n][k], zero-pad n>=40
    }
  } else {
    for (int i = t; i < NB; i += 256) bcursor[i] = i * CAP;
  }
}

// ---------------- bucketed CSR construction ----------------

__global__ __launch_bounds__(256) void k_bucket(const int* __restrict__ ei,
                                                int* __restrict__ bcursor,
                                                uint* __restrict__ pbuf) {
  __shared__ int cnt[NB];
  __shared__ int base[NB];
  const int tid = threadIdx.x;
  const int ebase = blockIdx.x * BCH;
  for (int t = tid; t < NB; t += 256) cnt[t] = 0;
  __syncthreads();
#pragma unroll 4
  for (int k = 0; k < BCH / 256; ++k) {
    int e = ebase + tid + k * 256;
    if (e < E2) {
      int d = (e < N_EDGES) ? ei[N_EDGES + e] : (e - N_EDGES);
      atomicAdd(&cnt[d >> 8], 1);
    }
  }
  __syncthreads();
  for (int t = tid; t < NB; t += 256) {
    int c = cnt[t];
    base[t] = c ? atomicAdd(&bcursor[t], c) : 0;
    cnt[t] = 0;
  }
  __syncthreads();
#pragma unroll 4
  for (int k = 0; k < BCH / 256; ++k) {
    int e = ebase + tid + k * 256;
    if (e < E2) {
      int s, d;
      if (e < N_EDGES) { s = ei[e]; d = ei[N_EDGES + e]; }
      else { s = e - N_EDGES; d = s; }
      int b = d >> 8;
      int pos = base[b] + atomicAdd(&cnt[b], 1);
      pbuf[pos] = ((uint)s << 8) | (uint)(d & 255);
    }
  }
}

__global__ __launch_bounds__(512) void k_scanB(const int* __restrict__ bcursor,
                                               int* __restrict__ bbase,
                                               int* __restrict__ rowptr) {
  __shared__ int sm[512];
  int t = threadIdx.x;
  int v = (t < NB) ? (bcursor[t] - t * CAP) : 0;
  sm[t] = v;
  __syncthreads();
  for (int off = 1; off < 512; off <<= 1) {
    int u = (t >= off) ? sm[t - off] : 0;
    __syncthreads();
    sm[t] += u;
    __syncthreads();
  }
  if (t < NB) bbase[t] = sm[t] - v;   // exclusive
  if (t == 0) rowptr[N_NODES] = E2;
}

__global__ __launch_bounds__(256) void k_csr(const uint* __restrict__ pbuf,
                                             const int* __restrict__ bcursor,
                                             const int* __restrict__ bbase,
                                             int* __restrict__ rowptr,
                                             int* __restrict__ csr) {
  __shared__ int hist[NPB];
  __shared__ int excl[NPB];
  __shared__ int cur[NPB];
  __shared__ int lcsr[CAP];
  const int b = blockIdx.x;
  const int tid = threadIdx.x;
  int count = bcursor[b] - b * CAP;
  if (count > CAP) count = CAP;
  const int gbase = bbase[b];
  const uint* seg = pbuf + b * CAP;
  hist[tid] = 0;
  __syncthreads();
  for (int k = tid; k < count; k += 256) atomicAdd(&hist[seg[k] & 255u], 1);
  __syncthreads();
  int own = hist[tid];
  excl[tid] = own;
  __syncthreads();
  for (int off = 1; off < 256; off <<= 1) {
    int u = (tid >= off) ? excl[tid - off] : 0;
    __syncthreads();
    excl[tid] += u;
    __syncthreads();
  }
  int ex = excl[tid] - own;
  cur[tid] = ex;
  int node = b * NPB + tid;
  if (node < N_NODES) rowptr[node] = gbase + ex;
  __syncthreads();
  for (int k = tid; k < count; k += 256) {
    uint pk = seg[k];
    int nd = pk & 255u;
    int pos = atomicAdd(&cur[nd], 1);
    lcsr[pos] = (int)(pk >> 8);
  }
  __syncthreads();
  for (int k = tid; k < count; k += 256) csr[gbase + k] = lcsr[k];
}

// ---------------- GEMM 1 (MFMA f16) + fused alr1 ----------------

__global__ __launch_bounds__(256) void k_gemm1m(const float* __restrict__ x,
                                                const ushort* __restrict__ WT1,
                                                const float* __restrict__ attl,
                                                const float* __restrict__ attr,
                                                ushort* __restrict__ h1h,
                                                ushort* __restrict__ al1h,
                                                float* __restrict__ ar1) {
  __shared__ ushort stg[4][16][136];   // pad 128->136 (17 uint4/row)
  __shared__ h2_t attl_sm[64], attr_sm[64];
  const int tid = threadIdx.x;
  const int w = tid >> 6, l = tid & 63;
  const int r16 = l & 15, kq = l >> 4;
  const int rowbase = blockIdx.x * 64 + w * 16;
  if (tid < 64) attl_sm[tid] = pk2h(attl[2 * tid], attl[2 * tid + 1]);
  else if (tid < 128) { int t = tid - 64; attr_sm[t] = pk2h(attr[2 * t], attr[2 * t + 1]); }
  int arow = rowbase + r16;
  if (arow > N_NODES - 1) arow = N_NODES - 1;
  // A-frags: row arow, k = t*32 + kq*8 + (0..7), fp32 -> fp16
  f16x8 af[4];
  const float* xr = x + (size_t)arow * 128 + kq * 8;
#pragma unroll
  for (int t = 0; t < 4; ++t) {
    float4 a0 = *(const float4*)(xr + t * 32);
    float4 a1 = *(const float4*)(xr + t * 32 + 4);
    U8 u;
    u.h2[0] = pk2h(a0.x, a0.y); u.h2[1] = pk2h(a0.z, a0.w);
    u.h2[2] = pk2h(a1.x, a1.y); u.h2[3] = pk2h(a1.z, a1.w);
    af[t] = u.v;
  }
  f32x4 acc[8];
#pragma unroll
  for (int n = 0; n < 8; ++n) acc[n] = (f32x4){0.f, 0.f, 0.f, 0.f};
  const uint4* WT4 = (const uint4*)WT1;   // row = 16 uint4 (128 fp16)
#pragma unroll
  for (int t = 0; t < 4; ++t) {
#pragma unroll
    for (int n = 0; n < 8; ++n) {
      U8 b;
      b.q = WT4[(size_t)(n * 16 + r16) * 16 + t * 4 + kq];
      acc[n] = __builtin_amdgcn_mfma_f32_16x16x32_f16(af[t], b.v, acc[n], 0, 0, 0);
    }
  }
  // D: row = kq*4 + r, col = n*16 + r16
#pragma unroll
  for (int n = 0; n < 8; ++n) {
#pragma unroll
    for (int r = 0; r < 4; ++r) stg[w][kq * 4 + r][n * 16 + r16] = f2h(acc[n][r]);
  }
  __syncthreads();
  // coalesced row write-out
  uint4* H1 = (uint4*)h1h;
  const uint4* S = (const uint4*)stg[w];   // row stride 17 uint4
#pragma unroll
  for (int q = 0; q < 4; ++q) {
    int idx = l + q * 64;
    int row = idx >> 4, c4 = idx & 15;
    int grow = rowbase + row;
    if (grow < N_NODES) H1[(size_t)grow * 16 + c4] = S[row * 17 + c4];
  }
  // fused alr1: 128 (row,head) pairs per wave, 2 per lane
#pragma unroll
  for (int p = 0; p < 2; ++p) {
    int pidx = l + p * 64;
    int row = pidx >> 3, h = pidx & 7;
    int grow = rowbase + row;
    U8 a0, a1;
    a0.q = S[row * 17 + h * 2];
    a1.q = S[row * 17 + h * 2 + 1];
    float sl = 0.f, sr = 0.f;
#pragma unroll
    for (int k = 0; k < 4; ++k) {
      sl = fdot2(a0.h2[k], attl_sm[h * 8 + k], sl);
      sr = fdot2(a0.h2[k], attr_sm[h * 8 + k], sr);
      sl = fdot2(a1.h2[k], attl_sm[h * 8 + 4 + k], sl);
      sr = fdot2(a1.h2[k], attr_sm[h * 8 + 4 + k], sr);
    }
    if (grow < N_NODES) {
      al1h[(size_t)grow * 8 + h] = f2h(sl);
      ar1[(size_t)grow * 8 + h] = sr;
    }
  }
}

// ---------------- edge pass, layer 1: one node per 16-lane group, 4-edge unroll ----------------

__global__ __launch_bounds__(256) void k_edge1(const ushort* __restrict__ h1h,
                                               const ushort* __restrict__ al1h,
                                               const float* __restrict__ ar1,
                                               const int* __restrict__ rowptr,
                                               const int* __restrict__ csr,
                                               const float* __restrict__ b1,
                                               ushort* __restrict__ y1h) {
  const int tid = threadIdx.x;
  const int lane = tid & 63;
  const int wv = tid >> 6;         // wave in block (0..3)
  const int grp = lane >> 4;       // group 0..3, one node each
  const int l = lane & 15;         // channel slot: ch l*8 .. l*8+7
  const int h = l >> 1;            // head
  const int node0 = (blockIdx.x * 4 + wv) * 4 + grp;
  const bool alive = node0 < N_NODES;
  const int i = alive ? node0 : N_NODES - 1;
  const int start = rowptr[i], end = rowptr[i + 1];
  const uint4* H = (const uint4*)h1h;   // row = 16 uint4
  U8 uhi;
  uhi.q = H[(size_t)i * 16 + l];
  const float ar_i = ar1[i * 8 + h];
  float s = 0.f;
  float acc[8] = {};
  for (int e = start; e < end; e += 4) {
    int e1 = e + 1 < end ? e + 1 : end - 1;
    int e2 = e + 2 < end ? e + 2 : end - 1;
    int e3 = e + 3 < end ? e + 3 : end - 1;
    int j0 = csr[e], j1 = csr[e1], j2 = csr[e2], j3 = csr[e3];
    U8 u0, u1, u2, u3;
    u0.q = H[(size_t)j0 * 16 + l];
    u1.q = H[(size_t)j1 * 16 + l];
    u2.q = H[(size_t)j2 * 16 + l];
    u3.q = H[(size_t)j3 * 16 + l];
    float al0 = h2f(al1h[j0 * 8 + h]);
    float al1 = h2f(al1h[j1 * 8 + h]);
    float al2 = h2f(al1h[j2 * 8 + h]);
    float al3 = h2f(al1h[j3 * 8 + h]);
    float p0 = 0.f, p1 = 0.f, p2 = 0.f, p3 = 0.f;
#pragma unroll
    for (int k = 0; k < 4; ++k) {
      p0 = fdot2(uhi.h2[k], u0.h2[k], p0);
      p1 = fdot2(uhi.h2[k], u1.h2[k], p1);
      p2 = fdot2(uhi.h2[k], u2.h2[k], p2);
      p3 = fdot2(uhi.h2[k], u3.h2[k], p3);
    }
    p0 += __shfl_xor(p0, 1);
    p1 += __shfl_xor(p1, 1);
    p2 += __shfl_xor(p2, 1);
    p3 += __shfl_xor(p3, 1);
    float a0 = (al0 + ar_i) * (1.f / (1.f + __expf(-p0)));
    float a1 = (al1 + ar_i) * (1.f / (1.f + __expf(-p1)));
    float a2 = (al2 + ar_i) * (1.f / (1.f + __expf(-p2)));
    float a3 = (al3 + ar_i) * (1.f / (1.f + __expf(-p3)));
    a0 = fmaxf(a0, NEG_SLOPE * a0);
    a1 = fmaxf(a1, NEG_SLOPE * a1);
    a2 = fmaxf(a2, NEG_SLOPE * a2);
    a3 = fmaxf(a3, NEG_SLOPE * a3);
    float ex0 = __expf(a0);
    float ex1 = (e + 1 < end) ? __expf(a1) : 0.f;
    float ex2 = (e + 2 < end) ? __expf(a2) : 0.f;
    float ex3 = (e + 3 < end) ? __expf(a3) : 0.f;
    s += (ex0 + ex1) + (ex2 + ex3);
#pragma unroll
    for (int c = 0; c < 8; ++c) {
      float t0 = fmaf(ex0, (float)u0.h[c], ex1 * (float)u1.h[c]);
      float t1 = fmaf(ex2, (float)u2.h[c], ex3 * (float)u3.h[c]);
      acc[c] += t0 + t1;
    }
  }
  // epilogue: no cross-group merge needed (acc/s are group-local)
  float inv = 1.f / s;
  float4 bb0 = *(const float4*)(b1 + l * 8);
  float4 bb1 = *(const float4*)(b1 + l * 8 + 4);
  float o[8];
  o[0] = acc[0] * inv + bb0.x; o[1] = acc[1] * inv + bb0.y;
  o[2] = acc[2] * inv + bb0.z; o[3] = acc[3] * inv + bb0.w;
  o[4] = acc[4] * inv + bb1.x; o[5] = acc[5] * inv + bb1.y;
  o[6] = acc[6] * inv + bb1.z; o[7] = acc[7] * inv + bb1.w;
#pragma unroll
  for (int c = 0; c < 8; ++c) o[c] = o[c] > 0.f ? o[c] : __expf(o[c]) - 1.f;  // ELU
  if (alive) {
    U8 pk;
#pragma unroll
    for (int c = 0; c < 4; ++c) pk.h2[c] = pk2h(o[2 * c], o[2 * c + 1]);
    ((uint4*)y1h)[(size_t)i * 16 + l] = pk.q;
  }
}

// ---------------- GEMM 2 (MFMA f16) + fused alr2 ----------------

__global__ __launch_bounds__(256) void k_gemm2m(const ushort* __restrict__ y1h,
                                                const ushort* __restrict__ WT2,
                                                const float* __restrict__ attl,
                                                const float* __restrict__ attr,
                                                ushort* __restrict__ h2p,
                                                float* __restrict__ al2,
                                                float* __restrict__ ar2) {
  __shared__ ushort stg[4][16][56];    // pad 48->56 (7 uint4/row)
  __shared__ h2_t attl_sm[20], attr_sm[20];
  const int tid = threadIdx.x;
  const int w = tid >> 6, l = tid & 63;
  const int r16 = l & 15, kq = l >> 4;
  const int rowbase = blockIdx.x * 64 + w * 16;
  if (tid < 20) attl_sm[tid] = pk2h(attl[2 * tid], attl[2 * tid + 1]);
  else if (tid >= 32 && tid < 52) { int t = tid - 32; attr_sm[t] = pk2h(attr[2 * t], attr[2 * t + 1]); }
  int arow = rowbase + r16;
  if (arow > N_NODES - 1) arow = N_NODES - 1;
  const uint4* Y4 = (const uint4*)y1h;   // row = 16 uint4
  f16x8 af[4];
#pragma unroll
  for (int t = 0; t < 4; ++t) {
    U8 u;
    u.q = Y4[(size_t)arow * 16 + t * 4 + kq];
    af[t] = u.v;
  }
  f32x4 acc[3];
#pragma unroll
  for (int n = 0; n < 3; ++n) acc[n] = (f32x4){0.f, 0.f, 0.f, 0.f};
  const uint4* WT4 = (const uint4*)WT2;   // 48 rows x 16 uint4
#pragma unroll
  for (int t = 0; t < 4; ++t) {
#pragma unroll
    for (int n = 0; n < 3; ++n) {
      U8 b;
      b.q = WT4[(size_t)(n * 16 + r16) * 16 + t * 4 + kq];
      acc[n] = __builtin_amdgcn_mfma_f32_16x16x32_f16(af[t], b.v, acc[n], 0, 0, 0);
    }
  }
#pragma unroll
  for (int n = 0; n < 3; ++n) {
#pragma unroll
    for (int r = 0; r < 4; ++r) stg[w][kq * 4 + r][n * 16 + r16] = f2h(acc[n][r]);
  }
  __syncthreads();
  uint4* H2 = (uint4*)h2p;               // row = 8 uint4 (64 fp16)
  const uint4* S = (const uint4*)stg[w]; // row stride 7 uint4
  const uint4 z = make_uint4(0, 0, 0, 0);
#pragma unroll
  for (int q = 0; q < 2; ++q) {
    int idx = l + q * 64;                // 0..127
    int row = idx >> 3, c4 = idx & 7;
    int grow = rowbase + row;
    if (grow < N_NODES) H2[(size_t)grow * 8 + c4] = (c4 < 6) ? S[row * 7 + c4] : z;
  }
  // fused alr2: 16 rows x {al, ar} = 32 tasks on lanes 0..31
  if (l < 32) {
    int row = l & 15, sel = l >> 4;
    int grow = rowbase + row;
    const h2_t* att = sel ? attr_sm : attl_sm;
    float v = 0.f;
#pragma unroll
    for (int q = 0; q < 5; ++q) {
      U8 b;
      b.q = S[row * 7 + q];
#pragma unroll
      for (int k = 0; k < 4; ++k) v = fdot2(b.h2[k], att[q * 4 + k], v);
    }
    if (grow < N_NODES) {
      if (sel) ar2[grow] = v;
      else     al2[grow] = v;
    }
  }
}

// ---------------- edge pass, layer 2: one node per 8-lane group, 4-edge unroll + log_softmax ----------------

__global__ __launch_bounds__(256) void k_edge2(const ushort* __restrict__ h2p,
                                               const float* __restrict__ al,
                                               const float* __restrict__ ar,
                                               const int* __restrict__ rowptr,
                                               const int* __restrict__ csr,
                                               const float* __restrict__ b2,
                                               float* __restrict__ out) {
  const int tid = threadIdx.x;
  const int lane = tid & 63;
  const int wv = tid >> 6;         // wave in block (0..3)
  const int grp = lane >> 3;       // group 0..7, one node each
  const int l = lane & 7;          // channel slot (pads >= 40 are zero)
  const int node0 = (blockIdx.x * 4 + wv) * 8 + grp;
  const bool alive = node0 < N_NODES;
  const int i = alive ? node0 : N_NODES - 1;
  const int start = rowptr[i], end = rowptr[i + 1];
  const uint4* H = (const uint4*)h2p;   // row = 8 uint4
  U8 uhi;
  uhi.q = H[(size_t)i * 8 + l];
  const float ar_i = ar[i];
  float s = 0.f;
  float acc[8] = {};
  for (int e = start; e < end; e += 4) {
    int e1 = e + 1 < end ? e + 1 : end - 1;
    int e2 = e + 2 < end ? e + 2 : end - 1;
    int e3 = e + 3 < end ? e + 3 : end - 1;
    int j0 = csr[e], j1 = csr[e1], j2 = csr[e2], j3 = csr[e3];
    U8 u0, u1, u2, u3;
    u0.q = H[(size_t)j0 * 8 + l];
    u1.q = H[(size_t)j1 * 8 + l];
    u2.q = H[(size_t)j2 * 8 + l];
    u3.q = H[(size_t)j3 * 8 + l];
    float al0 = al[j0], al1 = al[j1], al2 = al[j2], al3 = al[j3];
    float p0 = 0.f, p1 = 0.f, p2 = 0.f, p3 = 0.f;
#pragma unroll
    for (int k = 0; k < 4; ++k) {
      p0 = fdot2(uhi.h2[k], u0.h2[k], p0);
      p1 = fdot2(uhi.h2[k], u1.h2[k], p1);
      p2 = fdot2(uhi.h2[k], u2.h2[k], p2);
      p3 = fdot2(uhi.h2[k], u3.h2[k], p3);
    }
#pragma unroll
    for (int m = 1; m <= 4; m <<= 1) {
      p0 += __shfl_xor(p0, m);
      p1 += __shfl_xor(p1, m);
      p2 += __shfl_xor(p2, m);
      p3 += __shfl_xor(p3, m);
    }
    float a0 = (al0 + ar_i) * (1.f / (1.f + __expf(-p0)));
    float a1 = (al1 + ar_i) * (1.f / (1.f + __expf(-p1)));
    float a2 = (al2 + ar_i) * (1.f / (1.f + __expf(-p2)));
    float a3 = (al3 + ar_i) * (1.f / (1.f + __expf(-p3)));
    a0 = fmaxf(a0, NEG_SLOPE * a0);
    a1 = fmaxf(a1, NEG_SLOPE * a1);
    a2 = fmaxf(a2, NEG_SLOPE * a2);
    a3 = fmaxf(a3, NEG_SLOPE * a3);
    float ex0 = __expf(a0);
    float ex1 = (e + 1 < end) ? __expf(a1) : 0.f;
    float ex2 = (e + 2 < end) ? __expf(a2) : 0.f;
    float ex3 = (e + 3 < end) ? __expf(a3) : 0.f;
    s += (ex0 + ex1) + (ex2 + ex3);
#pragma unroll
    for (int c = 0; c < 8; ++c) {
      float t0 = fmaf(ex0, (float)u0.h[c], ex1 * (float)u1.h[c]);
      float t1 = fmaf(ex2, (float)u2.h[c], ex3 * (float)u3.h[c]);
      acc[c] += t0 + t1;
    }
  }
  // epilogue: bias + log_softmax over 40 classes (group-local; lanes l<5 hold real channels)
  float inv = 1.f / s;
  bool act = l < 5;
  float o[8];
  float mx = -1e30f;
#pragma unroll
  for (int c = 0; c < 8; ++c) {
    float b = act ? b2[l * 8 + c] : 0.f;
    o[c] = acc[c] * inv + b;
    if (act) mx = fmaxf(mx, o[c]);
  }
  mx = fmaxf(mx, __shfl_xor(mx, 1));
  mx = fmaxf(mx, __shfl_xor(mx, 2));
  mx = fmaxf(mx, __shfl_xor(mx, 4));
  float se = 0.f;
  if (act) {
#pragma unroll
    for (int c = 0; c < 8; ++c) se += __expf(o[c] - mx);
  }
  se += __shfl_xor(se, 1);
  se += __shfl_xor(se, 2);
  se += __shfl_xor(se, 4);
  if (alive && act) {
    float lse = mx + __logf(se);
    float4 r0 = make_float4(o[0] - lse, o[1] - lse, o[2] - lse, o[3] - lse);
    float4 r1 = make_float4(o[4] - lse, o[5] - lse, o[6] - lse, o[7] - lse);
    float4* O = (float4*)(out + (size_t)i * 40 + l * 8);
    O[0] = r0;
    O[1] = r1;
  }
}

// ---------------- launcher ----------------

extern "C" void kernel_launch(void* const* d_in, const int* in_sizes, int n_in,
                              void* d_out, int out_size, void* d_ws, size_t ws_size,
                              hipStream_t stream) {
  const float* x     = (const float*)d_in[0];
  const int*   ei    = (const int*)d_in[1];
  const float* W1    = (const float*)d_in[2];
  const float* attl1 = (const float*)d_in[3];
  const float* attr1 = (const float*)d_in[4];
  const float* b1    = (const float*)d_in[5];
  const float* W2    = (const float*)d_in[6];
  const float* attl2 = (const float*)d_in[7];
  const float* attr2 = (const float*)d_in[8];
  const float* b2    = (const float*)d_in[9];
  float* out = (float*)d_out;

  char* wsp = (char*)d_ws;
  size_t off = 0;
  auto alloc = [&](size_t bytes) {
    char* p = wsp + off;
    off = (off + bytes + 255) & ~(size_t)255;
    return p;
  };
  ushort* h1h   = (ushort*)alloc((size_t)N_NODES * 128 * 2);  // fp16 h1
  ushort* y1h   = (ushort*)alloc((size_t)N_NODES * 128 * 2);  // fp16 y1
  ushort* al1h  = (ushort*)alloc((size_t)N_NODES * 8 * 2);    // fp16 al1
  float* ar1    = (float*)alloc((size_t)N_NODES * 8 * 4);
  int* rowptr   = (int*)alloc((size_t)(N_NODES + 1) * 4);
  int* bcursor  = (int*)alloc((size_t)NB * 4);
  int* bbase    = (int*)alloc((size_t)NB * 4);
  int* csr      = (int*)alloc((size_t)E2 * 4);
  ushort* WT1   = (ushort*)alloc(128 * 128 * 2);
  ushort* WT2   = (ushort*)alloc(48 * 128 * 2);
  uint* pbuf  = (uint*)y1h;   // overlay: pbuf (7.5MB) dead before edge1 writes y1h
  ushort* h2p = h1h;          // reuse: h1h dead after edge1
  float* al2  = (float*)ar1;  // reuse: ar1/al1h dead after edge1
  float* ar2  = al2 + N_NODES;

  // prep + CSR build
  k_prepW<<<3, 256, 0, stream>>>(W1, W2, WT1, WT2, bcursor);
  k_bucket<<<(E2 + BCH - 1) / BCH, 256, 0, stream>>>(ei, bcursor, pbuf);
  k_scanB<<<1, 512, 0, stream>>>(bcursor, bbase, rowptr);
  k_csr<<<NB, 256, 0, stream>>>(pbuf, bcursor, bbase, rowptr, csr);

  // layer 1
  k_gemm1m<<<(N_NODES + 63) / 64, 256, 0, stream>>>(x, WT1, attl1, attr1, h1h, al1h, ar1);
  k_edge1<<<(N_NODES + 15) / 16, 256, 0, stream>>>(h1h, al1h, ar1, rowptr, csr, b1, y1h);

  // layer 2
  k_gemm2m<<<(N_NODES + 63) / 64, 256, 0, stream>>>(y1h, WT2, attl2, attr2, h2p, al2, ar2);
  k_edge2<<<(N_NODES + 31) / 32, 256, 0, stream>>>(h2p, al2, ar2, rowptr, csr, b2, out);
}

// Round 8
// 232.599 us; speedup vs baseline: 3.2709x; 1.0828x over previous
//
#include <hip/hip_runtime.h>
#include <math.h>

#define N_NODES 100000
#define N_EDGES 1600000
#define E2 (N_EDGES + N_NODES)
#define NEG_SLOPE 0.2f

#define NPB 256                      // nodes per bucket
#define NB  ((N_NODES + NPB - 1) / NPB)   // 391 buckets
#define CAP 4800                     // per-bucket raw edge capacity
#define CAPP (CAP + 3 * NPB)         // padded capacity (5568)
#define BSLACK 772                   // per-bucket slack in final CSR (768 pad + 4 align)
#define BCH 8192                     // edges per block in k_bucket

typedef unsigned int uint;
typedef unsigned short ushort;
typedef __attribute__((ext_vector_type(2))) _Float16 h2_t;
typedef __attribute__((ext_vector_type(8))) _Float16 f16x8;
typedef __attribute__((ext_vector_type(4))) float f32x4;

union U8 { uint4 q; f16x8 v; h2_t h2[4]; _Float16 h[8]; uint u[4]; };

// ---------------- fp16 helpers ----------------

__device__ inline ushort f2h(float x) {
  _Float16 h = (_Float16)x;
  return *(ushort*)&h;
}

__device__ inline float h2f(ushort u) {
  _Float16 h = *(_Float16*)&u;
  return (float)h;
}

__device__ inline h2_t pk2h(float a, float b) {
  auto r = __builtin_amdgcn_cvt_pkrtz(a, b);   // __fp16 vec2 -> bit-cast
  return *(h2_t*)&r;
}

__device__ inline float fdot2(h2_t a, h2_t b, float c) {
#if __has_builtin(__builtin_amdgcn_fdot2)
  return __builtin_amdgcn_fdot2(*(__fp16 __attribute__((ext_vector_type(2)))*)&a,
                                *(__fp16 __attribute__((ext_vector_type(2)))*)&b,
                                c, false);
#else
  return c + (float)a.x * (float)b.x + (float)a.y * (float)b.y;
#endif
}

// ---------------- prep: W transposes (fp16) + bucket cursor init ----------------

__global__ __launch_bounds__(256) void k_prepW(const float* __restrict__ W1,
                                               const float* __restrict__ W2,
                                               ushort* __restrict__ WT1,
                                               ushort* __restrict__ WT2,
                                               int* __restrict__ bcursor) {
  int b = blockIdx.x, t = threadIdx.x;
  if (b == 0) {
    for (int i = t; i < 128 * 128; i += 256) {
      int k = i >> 7, n = i & 127;
      WT1[n * 128 + k] = f2h(W1[i]);           // WT1[n][k]
    }
  } else if (b == 1) {
    for (int i = t; i < 48 * 128; i += 256) {
      int n = i >> 7, k = i & 127;
      WT2[i] = (n < 40) ? f2h(W2[k * 40 + n]) : (ushort)0;   // WT2[n][k], zero-pad n>=40
    }
  } else {
    for (int i = t; i < NB; i += 256) bcursor[i] = i * CAP;
  }
}

// ---------------- bucketed CSR construction ----------------

__global__ __launch_bounds__(256) void k_bucket(const int* __restrict__ ei,
                                                int* __restrict__ bcursor,
                                                uint* __restrict__ pbuf) {
  __shared__ int cnt[NB];
  __shared__ int base[NB];
  const int tid = threadIdx.x;
  const int ebase = blockIdx.x * BCH;
  for (int t = tid; t < NB; t += 256) cnt[t] = 0;
  __syncthreads();
#pragma unroll 4
  for (int k = 0; k < BCH / 256; ++k) {
    int e = ebase + tid + k * 256;
    if (e < E2) {
      int d = (e < N_EDGES) ? ei[N_EDGES + e] : (e - N_EDGES);
      atomicAdd(&cnt[d >> 8], 1);
    }
  }
  __syncthreads();
  for (int t = tid; t < NB; t += 256) {
    int c = cnt[t];
    base[t] = c ? atomicAdd(&bcursor[t], c) : 0;
    cnt[t] = 0;
  }
  __syncthreads();
#pragma unroll 4
  for (int k = 0; k < BCH / 256; ++k) {
    int e = ebase + tid + k * 256;
    if (e < E2) {
      int s, d;
      if (e < N_EDGES) { s = ei[e]; d = ei[N_EDGES + e]; }
      else { s = e - N_EDGES; d = s; }
      int b = d >> 8;
      int pos = base[b] + atomicAdd(&cnt[b], 1);
      pbuf[pos] = ((uint)s << 8) | (uint)(d & 255);
    }
  }
}

__global__ __launch_bounds__(512) void k_scanB(const int* __restrict__ bcursor,
                                               int* __restrict__ bbase) {
  __shared__ int sm[512];
  int t = threadIdx.x;
  int v = (t < NB) ? (bcursor[t] - t * CAP) : 0;
  sm[t] = v;
  __syncthreads();
  for (int off = 1; off < 512; off <<= 1) {
    int u = (t >= off) ? sm[t - off] : 0;
    __syncthreads();
    sm[t] += u;
    __syncthreads();
  }
  if (t < NB) {
    int excl = sm[t] - v;
    bbase[t] = ((excl + 3) & ~3) + t * BSLACK;   // 16B-aligned start + per-bucket pad slack
  }
}

// Pass B: per-bucket CSR with per-node padding to multiple of 4 (sentinel = N_NODES).
__global__ __launch_bounds__(256) void k_csr(const uint* __restrict__ pbuf,
                                             const int* __restrict__ bcursor,
                                             const int* __restrict__ bbase,
                                             int* __restrict__ rs,
                                             int* __restrict__ re,
                                             int* __restrict__ csr) {
  __shared__ int hist[NPB];
  __shared__ int excl[NPB];
  __shared__ int cur[NPB];
  __shared__ int lcsr[CAPP];
  const int b = blockIdx.x;
  const int tid = threadIdx.x;
  int count = bcursor[b] - b * CAP;
  if (count > CAP) count = CAP;
  const int gbase = bbase[b];
  const uint* seg = pbuf + b * CAP;
  hist[tid] = 0;
  __syncthreads();
  for (int k = tid; k < count; k += 256) atomicAdd(&hist[seg[k] & 255u], 1);
  __syncthreads();
  int rounded = (hist[tid] + 3) & ~3;          // pad each node to multiple of 4
  excl[tid] = rounded;
  __syncthreads();
  for (int off = 1; off < 256; off <<= 1) {
    int u = (tid >= off) ? excl[tid - off] : 0;
    __syncthreads();
    excl[tid] += u;
    __syncthreads();
  }
  int ex = excl[tid] - rounded;
  cur[tid] = ex;
  int node = b * NPB + tid;
  if (node < N_NODES) {
    rs[node] = gbase + ex;
    re[node] = gbase + ex + rounded;
  }
  __syncthreads();
  const int ptotal = excl[NPB - 1];
  // init padded region with sentinel
  for (int k = tid; k < ptotal; k += 256) lcsr[k] = N_NODES;
  __syncthreads();
  // scatter real edges
  for (int k = tid; k < count; k += 256) {
    uint pk = seg[k];
    int nd = pk & 255u;
    int pos = atomicAdd(&cur[nd], 1);
    lcsr[pos] = (int)(pk >> 8);
  }
  __syncthreads();
  for (int k = tid; k < ptotal; k += 256) csr[gbase + k] = lcsr[k];
}

// ---------------- GEMM 1 (MFMA f16) + fused alr1 + sentinel init ----------------

__global__ __launch_bounds__(256) void k_gemm1m(const float* __restrict__ x,
                                                const ushort* __restrict__ WT1,
                                                const float* __restrict__ attl,
                                                const float* __restrict__ attr,
                                                ushort* __restrict__ h1h,
                                                ushort* __restrict__ al1h,
                                                float* __restrict__ ar1) {
  __shared__ ushort stg[4][16][136];   // pad 128->136 (17 uint4/row)
  __shared__ h2_t attl_sm[64], attr_sm[64];
  const int tid = threadIdx.x;
  const int w = tid >> 6, l = tid & 63;
  const int r16 = l & 15, kq = l >> 4;
  const int rowbase = blockIdx.x * 64 + w * 16;
  if (tid < 64) attl_sm[tid] = pk2h(attl[2 * tid], attl[2 * tid + 1]);
  else if (tid < 128) { int t = tid - 64; attr_sm[t] = pk2h(attr[2 * t], attr[2 * t + 1]); }
  if (blockIdx.x == 0) {   // sentinel row N_NODES: h=0, al=-inf
    if (tid >= 128 && tid < 144) ((uint4*)h1h)[(size_t)N_NODES * 16 + (tid - 128)] = make_uint4(0, 0, 0, 0);
    else if (tid >= 144 && tid < 152) al1h[(size_t)N_NODES * 8 + (tid - 144)] = (ushort)0xFC00;  // fp16 -inf
  }
  int arow = rowbase + r16;
  if (arow > N_NODES - 1) arow = N_NODES - 1;
  f16x8 af[4];
  const float* xr = x + (size_t)arow * 128 + kq * 8;
#pragma unroll
  for (int t = 0; t < 4; ++t) {
    float4 a0 = *(const float4*)(xr + t * 32);
    float4 a1 = *(const float4*)(xr + t * 32 + 4);
    U8 u;
    u.h2[0] = pk2h(a0.x, a0.y); u.h2[1] = pk2h(a0.z, a0.w);
    u.h2[2] = pk2h(a1.x, a1.y); u.h2[3] = pk2h(a1.z, a1.w);
    af[t] = u.v;
  }
  f32x4 acc[8];
#pragma unroll
  for (int n = 0; n < 8; ++n) acc[n] = (f32x4){0.f, 0.f, 0.f, 0.f};
  const uint4* WT4 = (const uint4*)WT1;   // row = 16 uint4 (128 fp16)
#pragma unroll
  for (int t = 0; t < 4; ++t) {
#pragma unroll
    for (int n = 0; n < 8; ++n) {
      U8 b;
      b.q = WT4[(size_t)(n * 16 + r16) * 16 + t * 4 + kq];
      acc[n] = __builtin_amdgcn_mfma_f32_16x16x32_f16(af[t], b.v, acc[n], 0, 0, 0);
    }
  }
#pragma unroll
  for (int n = 0; n < 8; ++n) {
#pragma unroll
    for (int r = 0; r < 4; ++r) stg[w][kq * 4 + r][n * 16 + r16] = f2h(acc[n][r]);
  }
  __syncthreads();
  uint4* H1 = (uint4*)h1h;
  const uint4* S = (const uint4*)stg[w];   // row stride 17 uint4
#pragma unroll
  for (int q = 0; q < 4; ++q) {
    int idx = l + q * 64;
    int row = idx >> 4, c4 = idx & 15;
    int grow = rowbase + row;
    if (grow < N_NODES) H1[(size_t)grow * 16 + c4] = S[row * 17 + c4];
  }
#pragma unroll
  for (int p = 0; p < 2; ++p) {
    int pidx = l + p * 64;
    int row = pidx >> 3, h = pidx & 7;
    int grow = rowbase + row;
    U8 a0, a1;
    a0.q = S[row * 17 + h * 2];
    a1.q = S[row * 17 + h * 2 + 1];
    float sl = 0.f, sr = 0.f;
#pragma unroll
    for (int k = 0; k < 4; ++k) {
      sl = fdot2(a0.h2[k], attl_sm[h * 8 + k], sl);
      sr = fdot2(a0.h2[k], attr_sm[h * 8 + k], sr);
      sl = fdot2(a1.h2[k], attl_sm[h * 8 + 4 + k], sl);
      sr = fdot2(a1.h2[k], attr_sm[h * 8 + 4 + k], sr);
    }
    if (grow < N_NODES) {
      al1h[(size_t)grow * 8 + h] = f2h(sl);
      ar1[(size_t)grow * 8 + h] = sr;
    }
  }
}

// ---------------- edge pass, layer 1: node per 16-lane group, padded 4-edge steps ----------------

__global__ __launch_bounds__(256) void k_edge1(const ushort* __restrict__ h1h,
                                               const ushort* __restrict__ alT,
                                               const float* __restrict__ ar1,
                                               const int* __restrict__ rs,
                                               const int* __restrict__ re,
                                               const int* __restrict__ csr,
                                               const float* __restrict__ b1,
                                               ushort* __restrict__ y1h) {
  const int tid = threadIdx.x;
  const int lane = tid & 63;
  const int wv = tid >> 6;
  const int grp = lane >> 4;
  const int l = lane & 15;
  const int h = l >> 1;
  const int node0 = (blockIdx.x * 4 + wv) * 4 + grp;
  const bool alive = node0 < N_NODES;
  const int i = alive ? node0 : N_NODES - 1;
  const int start = rs[i], end = re[i];
  const char* Hb = (const char*)h1h;
  const char* Ab = (const char*)alT;
  const char* Cb = (const char*)csr;
  const uint loff = (uint)l * 16u;
  const uint aoff = (uint)h * 2u;
  U8 uhi;
  uhi.q = *(const uint4*)(Hb + (uint)i * 256u + loff);
  const float ar_i = ar1[i * 8 + h];
  float s = 0.f;
  f16x8 acc = {};
  for (int e = start; e < end; e += 4) {
    int4 j4 = *(const int4*)(Cb + (uint)e * 4u);
    U8 u0, u1, u2, u3;
    u0.q = *(const uint4*)(Hb + (uint)j4.x * 256u + loff);
    u1.q = *(const uint4*)(Hb + (uint)j4.y * 256u + loff);
    u2.q = *(const uint4*)(Hb + (uint)j4.z * 256u + loff);
    u3.q = *(const uint4*)(Hb + (uint)j4.w * 256u + loff);
    float av0 = h2f(*(const ushort*)(Ab + (uint)j4.x * 16u + aoff));
    float av1 = h2f(*(const ushort*)(Ab + (uint)j4.y * 16u + aoff));
    float av2 = h2f(*(const ushort*)(Ab + (uint)j4.z * 16u + aoff));
    float av3 = h2f(*(const ushort*)(Ab + (uint)j4.w * 16u + aoff));
    float p0 = 0.f, p1 = 0.f, p2 = 0.f, p3 = 0.f;
#pragma unroll
    for (int k = 0; k < 4; ++k) {
      p0 = fdot2(uhi.h2[k], u0.h2[k], p0);
      p1 = fdot2(uhi.h2[k], u1.h2[k], p1);
      p2 = fdot2(uhi.h2[k], u2.h2[k], p2);
      p3 = fdot2(uhi.h2[k], u3.h2[k], p3);
    }
    p0 += __shfl_xor(p0, 1);
    p1 += __shfl_xor(p1, 1);
    p2 += __shfl_xor(p2, 1);
    p3 += __shfl_xor(p3, 1);
    float a0 = (av0 + ar_i) * (1.f / (1.f + __expf(-p0)));
    float a1 = (av1 + ar_i) * (1.f / (1.f + __expf(-p1)));
    float a2 = (av2 + ar_i) * (1.f / (1.f + __expf(-p2)));
    float a3 = (av3 + ar_i) * (1.f / (1.f + __expf(-p3)));
    a0 = fmaxf(a0, NEG_SLOPE * a0);
    a1 = fmaxf(a1, NEG_SLOPE * a1);
    a2 = fmaxf(a2, NEG_SLOPE * a2);
    a3 = fmaxf(a3, NEG_SLOPE * a3);
    float ex0 = __expf(a0);   // sentinel: a=-inf -> ex=0
    float ex1 = __expf(a1);
    float ex2 = __expf(a2);
    float ex3 = __expf(a3);
    s += (ex0 + ex1) + (ex2 + ex3);
    acc += u0.v * (_Float16)ex0;
    acc += u1.v * (_Float16)ex1;
    acc += u2.v * (_Float16)ex2;
    acc += u3.v * (_Float16)ex3;
  }
  float inv = 1.f / s;
  float4 bb0 = *(const float4*)(b1 + l * 8);
  float4 bb1 = *(const float4*)(b1 + l * 8 + 4);
  float o[8];
#pragma unroll
  for (int c = 0; c < 8; ++c) {
    float b = (c < 4) ? ((const float*)&bb0)[c] : ((const float*)&bb1)[c - 4];
    float v = (float)acc[c] * inv + b;
    o[c] = v > 0.f ? v : __expf(v) - 1.f;       // ELU
  }
  if (alive) {
    U8 pk;
#pragma unroll
    for (int c = 0; c < 4; ++c) pk.h2[c] = pk2h(o[2 * c], o[2 * c + 1]);
    ((uint4*)y1h)[(size_t)i * 16 + l] = pk.q;
  }
}

// ---------------- GEMM 2 (MFMA f16) + fused alr2, compact 40ch (5 uint4) rows ----------------

__global__ __launch_bounds__(256) void k_gemm2m(const ushort* __restrict__ y1h,
                                                const ushort* __restrict__ WT2,
                                                const float* __restrict__ attl,
                                                const float* __restrict__ attr,
                                                ushort* __restrict__ h2p,
                                                float* __restrict__ al2,
                                                float* __restrict__ ar2) {
  __shared__ ushort stg[4][16][56];    // pad 48->56 (7 uint4/row)
  __shared__ h2_t attl_sm[20], attr_sm[20];
  const int tid = threadIdx.x;
  const int w = tid >> 6, l = tid & 63;
  const int r16 = l & 15, kq = l >> 4;
  const int rowbase = blockIdx.x * 64 + w * 16;
  if (tid < 20) attl_sm[tid] = pk2h(attl[2 * tid], attl[2 * tid + 1]);
  else if (tid >= 32 && tid < 52) { int t = tid - 32; attr_sm[t] = pk2h(attr[2 * t], attr[2 * t + 1]); }
  if (blockIdx.x == 0) {   // sentinel row: h2=0, al2=-inf
    if (tid >= 64 && tid < 69) ((uint4*)h2p)[(size_t)N_NODES * 5 + (tid - 64)] = make_uint4(0, 0, 0, 0);
    else if (tid == 69) al2[N_NODES] = -INFINITY;
  }
  int arow = rowbase + r16;
  if (arow > N_NODES - 1) arow = N_NODES - 1;
  const uint4* Y4 = (const uint4*)y1h;   // row = 16 uint4
  f16x8 af[4];
#pragma unroll
  for (int t = 0; t < 4; ++t) {
    U8 u;
    u.q = Y4[(size_t)arow * 16 + t * 4 + kq];
    af[t] = u.v;
  }
  f32x4 acc[3];
#pragma unroll
  for (int n = 0; n < 3; ++n) acc[n] = (f32x4){0.f, 0.f, 0.f, 0.f};
  const uint4* WT4 = (const uint4*)WT2;   // 48 rows x 16 uint4
#pragma unroll
  for (int t = 0; t < 4; ++t) {
#pragma unroll
    for (int n = 0; n < 3; ++n) {
      U8 b;
      b.q = WT4[(size_t)(n * 16 + r16) * 16 + t * 4 + kq];
      acc[n] = __builtin_amdgcn_mfma_f32_16x16x32_f16(af[t], b.v, acc[n], 0, 0, 0);
    }
  }
#pragma unroll
  for (int n = 0; n < 3; ++n) {
#pragma unroll
    for (int r = 0; r < 4; ++r) stg[w][kq * 4 + r][n * 16 + r16] = f2h(acc[n][r]);
  }
  __syncthreads();
  uint4* H2 = (uint4*)h2p;               // row = 5 uint4 (40 fp16, compact)
  const uint4* S = (const uint4*)stg[w]; // row stride 7 uint4
#pragma unroll
  for (int q = 0; q < 2; ++q) {
    int idx = l + q * 64;                // 0..127; active < 80
    if (idx < 80) {
      int row = idx / 5, c4 = idx % 5;
      int grow = rowbase + row;
      if (grow < N_NODES) H2[(size_t)grow * 5 + c4] = S[row * 7 + c4];
    }
  }
  // fused alr2: 16 rows x {al, ar} = 32 tasks on lanes 0..31
  if (l < 32) {
    int row = l & 15, sel = l >> 4;
    int grow = rowbase + row;
    const h2_t* att = sel ? attr_sm : attl_sm;
    float v = 0.f;
#pragma unroll
    for (int q = 0; q < 5; ++q) {
      U8 b;
      b.q = S[row * 7 + q];
#pragma unroll
      for (int k = 0; k < 4; ++k) v = fdot2(b.h2[k], att[q * 4 + k], v);
    }
    if (grow < N_NODES) {
      if (sel) ar2[grow] = v;
      else     al2[grow] = v;
    }
  }
}

// ---------------- edge pass, layer 2: node per 8-lane group, padded 4-edge steps + log_softmax ----------------

__global__ __launch_bounds__(256) void k_edge2(const ushort* __restrict__ h2p,
                                               const float* __restrict__ alT,
                                               const float* __restrict__ ar2,
                                               const int* __restrict__ rs,
                                               const int* __restrict__ re,
                                               const int* __restrict__ csr,
                                               const float* __restrict__ b2,
                                               float* __restrict__ out) {
  const int tid = threadIdx.x;
  const int lane = tid & 63;
  const int wv = tid >> 6;
  const int grp = lane >> 3;
  const int l = lane & 7;
  const int node0 = (blockIdx.x * 4 + wv) * 8 + grp;
  const bool alive = node0 < N_NODES;
  const int i = alive ? node0 : N_NODES - 1;
  const int start = rs[i], end = re[i];
  const char* Hb = (const char*)h2p;
  const char* Cb = (const char*)csr;
  const uint loff = (uint)(l < 5 ? l : 0) * 16u;   // lanes 5-7 duplicate uint4 0 (free, masked)
  U8 uhi;
  uhi.q = *(const uint4*)(Hb + (uint)i * 80u + loff);
  if (l >= 5) uhi.q = make_uint4(0, 0, 0, 0);      // mask -> dot contributions are 0
  const float ar_i = ar2[i];
  float s = 0.f;
  f16x8 acc = {};
  for (int e = start; e < end; e += 4) {
    int4 j4 = *(const int4*)(Cb + (uint)e * 4u);
    U8 u0, u1, u2, u3;
    u0.q = *(const uint4*)(Hb + (uint)j4.x * 80u + loff);
    u1.q = *(const uint4*)(Hb + (uint)j4.y * 80u + loff);
    u2.q = *(const uint4*)(Hb + (uint)j4.z * 80u + loff);
    u3.q = *(const uint4*)(Hb + (uint)j4.w * 80u + loff);
    float av0 = alT[j4.x];
    float av1 = alT[j4.y];
    float av2 = alT[j4.z];
    float av3 = alT[j4.w];
    float p0 = 0.f, p1 = 0.f, p2 = 0.f, p3 = 0.f;
#pragma unroll
    for (int k = 0; k < 4; ++k) {
      p0 = fdot2(uhi.h2[k], u0.h2[k], p0);
      p1 = fdot2(uhi.h2[k], u1.h2[k], p1);
      p2 = fdot2(uhi.h2[k], u2.h2[k], p2);
      p3 = fdot2(uhi.h2[k], u3.h2[k], p3);
    }
#pragma unroll
    for (int m = 1; m <= 4; m <<= 1) {
      p0 += __shfl_xor(p0, m);
      p1 += __shfl_xor(p1, m);
      p2 += __shfl_xor(p2, m);
      p3 += __shfl_xor(p3, m);
    }
    float a0 = (av0 + ar_i) * (1.f / (1.f + __expf(-p0)));
    float a1 = (av1 + ar_i) * (1.f / (1.f + __expf(-p1)));
    float a2 = (av2 + ar_i) * (1.f / (1.f + __expf(-p2)));
    float a3 = (av3 + ar_i) * (1.f / (1.f + __expf(-p3)));
    a0 = fmaxf(a0, NEG_SLOPE * a0);
    a1 = fmaxf(a1, NEG_SLOPE * a1);
    a2 = fmaxf(a2, NEG_SLOPE * a2);
    a3 = fmaxf(a3, NEG_SLOPE * a3);
    float ex0 = __expf(a0);   // sentinel: al=-inf -> ex=0
    float ex1 = __expf(a1);
    float ex2 = __expf(a2);
    float ex3 = __expf(a3);
    s += (ex0 + ex1) + (ex2 + ex3);
    acc += u0.v * (_Float16)ex0;
    acc += u1.v * (_Float16)ex1;
    acc += u2.v * (_Float16)ex2;
    acc += u3.v * (_Float16)ex3;
  }
  // epilogue: bias + log_softmax over 40 classes (group-local)
  float inv = 1.f / s;
  bool act = l < 5;
  float o[8];
  float mx = -1e30f;
#pragma unroll
  for (int c = 0; c < 8; ++c) {
    float b = act ? b2[l * 8 + c] : 0.f;
    o[c] = (float)acc[c] * inv + b;
    if (act) mx = fmaxf(mx, o[c]);
  }
  mx = fmaxf(mx, __shfl_xor(mx, 1));
  mx = fmaxf(mx, __shfl_xor(mx, 2));
  mx = fmaxf(mx, __shfl_xor(mx, 4));
  float se = 0.f;
  if (act) {
#pragma unroll
    for (int c = 0; c < 8; ++c) se += __expf(o[c] - mx);
  }
  se += __shfl_xor(se, 1);
  se += __shfl_xor(se, 2);
  se += __shfl_xor(se, 4);
  if (alive && act) {
    float lse = mx + __logf(se);
    float4 r0 = make_float4(o[0] - lse, o[1] - lse, o[2] - lse, o[3] - lse);
    float4 r1 = make_float4(o[4] - lse, o[5] - lse, o[6] - lse, o[7] - lse);
    float4* O = (float4*)(out + (size_t)i * 40 + l * 8);
    O[0] = r0;
    O[1] = r1;
  }
}

// ---------------- launcher ----------------

extern "C" void kernel_launch(void* const* d_in, const int* in_sizes, int n_in,
                              void* d_out, int out_size, void* d_ws, size_t ws_size,
                              hipStream_t stream) {
  const float* x     = (const float*)d_in[0];
  const int*   ei    = (const int*)d_in[1];
  const float* W1    = (const float*)d_in[2];
  const float* attl1 = (const float*)d_in[3];
  const float* attr1 = (const float*)d_in[4];
  const float* b1    = (const float*)d_in[5];
  const float* W2    = (const float*)d_in[6];
  const float* attl2 = (const float*)d_in[7];
  const float* attr2 = (const float*)d_in[8];
  const float* b2    = (const float*)d_in[9];
  float* out = (float*)d_out;

  char* wsp = (char*)d_ws;
  size_t off = 0;
  auto alloc = [&](size_t bytes) {
    char* p = wsp + off;
    off = (off + bytes + 255) & ~(size_t)255;
    return p;
  };
  ushort* h1h   = (ushort*)alloc((size_t)(N_NODES + 1) * 128 * 2);  // fp16 h1 (+sentinel row)
  ushort* y1h   = (ushort*)alloc((size_t)N_NODES * 128 * 2);        // fp16 y1
  ushort* al1h  = (ushort*)alloc((size_t)(N_NODES + 1) * 8 * 2);    // fp16 al1 (+sentinel)
  float* ar1    = (float*)alloc((size_t)N_NODES * 8 * 4);
  int* rs       = (int*)alloc((size_t)(N_NODES + 4) * 4);
  int* re       = (int*)alloc((size_t)(N_NODES + 4) * 4);
  int* bcursor  = (int*)alloc((size_t)NB * 4);
  int* bbase    = (int*)alloc((size_t)NB * 4);
  int* csr      = (int*)alloc((size_t)(E2 + NB * BSLACK + 16) * 4); // padded CSR
  ushort* WT1   = (ushort*)alloc(128 * 128 * 2);
  ushort* WT2   = (ushort*)alloc(48 * 128 * 2);
  uint* pbuf  = (uint*)y1h;   // overlay: pbuf (7.5MB) dead before edge1 writes y1h
  ushort* h2p = h1h;          // reuse: h1h dead after edge1 ((N+1)*80B <= (N+1)*256B)
  float* al2  = (float*)ar1;  // reuse: ar1/al1h dead after edge1; needs N+1 floats
  float* ar2  = al2 + N_NODES + 8;

  // prep + CSR build
  k_prepW<<<3, 256, 0, stream>>>(W1, W2, WT1, WT2, bcursor);
  k_bucket<<<(E2 + BCH - 1) / BCH, 256, 0, stream>>>(ei, bcursor, pbuf);
  k_scanB<<<1, 512, 0, stream>>>(bcursor, bbase);
  k_csr<<<NB, 256, 0, stream>>>(pbuf, bcursor, bbase, rs, re, csr);

  // layer 1
  k_gemm1m<<<(N_NODES + 63) / 64, 256, 0, stream>>>(x, WT1, attl1, attr1, h1h, al1h, ar1);
  k_edge1<<<(N_NODES + 15) / 16, 256, 0, stream>>>(h1h, al1h, ar1, rs, re, csr, b1, y1h);

  // layer 2
  k_gemm2m<<<(N_NODES + 63) / 64, 256, 0, stream>>>(y1h, WT2, attl2, attr2, h2p, al2, ar2);
  k_edge2<<<(N_NODES + 31) / 32, 256, 0, stream>>>(h2p, al2, ar2, rs, re, csr, b2, out);
}